// Round 6
// baseline (395.319 us; speedup 1.0000x reference)
//
#include <hip/hip_runtime.h>

#define B_ 2
#define C_ 256
#define IC_ 128
#define N_ 4096
#define KSEL 2048

// fixed workspace offsets (floats)
#define OFF_THETA 0u
#define OFF_PHI   1048576u
#define OFF_GW    2097152u
#define OFF_GC    3145728u
#define OFF_Y     4194304u          // 2M floats
#define OFF_WEFF  6291456u
#define OFF_BEFF  6324224u
#define OFF_MEAN  6324352u
#define OFF_RSIG  6324608u
#define OFF_CNT   6324864u
#define OFF_LIST  6324928u
#define OFF_DYN   6333440u          // S (+ gc_part) start here

__device__ __forceinline__ unsigned int f2u(float f) {
    unsigned int u = __float_as_uint(f);
    return (u & 0x80000000u) ? ~u : (u | 0x80000000u);
}

// ---------------------------------------------------------------------------
// Weff[o][c] = sum_i Wgcn[i][o] * Wg[i][c];  beff[o] = sum_i Wgcn[i][o]*bg[i]
// ---------------------------------------------------------------------------
__global__ __launch_bounds__(256) void weff_kernel(
    const float* __restrict__ Wg, const float* __restrict__ bg,
    const float* __restrict__ Wgcn, float* __restrict__ Weff,
    float* __restrict__ beff)
{
    const int o = blockIdx.x, c = threadIdx.x;
    float acc = 0.f;
    for (int i = 0; i < IC_; ++i)
        acc = fmaf(Wgcn[i * IC_ + o], Wg[i * C_ + c], acc);
    Weff[o * C_ + c] = acc;
    if (c == 0) {
        float bacc = 0.f;
        for (int i = 0; i < IC_; ++i)
            bacc = fmaf(Wgcn[i * IC_ + o], bg[i], bacc);
        beff[o] = bacc;
    }
}

// ---------------------------------------------------------------------------
// Projections as tiled GEMM: {theta, gW(=Weff proj), phi} from x.
// ---------------------------------------------------------------------------
__global__ __launch_bounds__(256) void proj_kernel(
    const float* __restrict__ x,
    const float* __restrict__ Wth, const float* __restrict__ bth,
    const float* __restrict__ Weff, const float* __restrict__ beff,
    const float* __restrict__ Wph, const float* __restrict__ bph,
    float* __restrict__ theta, float* __restrict__ gW, float* __restrict__ phi)
{
    __shared__ float Xs[32][65];
    __shared__ float Ws[64][33];
    const int oc    = blockIdx.x;
    const int n0    = blockIdx.y * 64;
    const int b     = blockIdx.z;
    const int proj  = oc >> 1;
    const int orow0 = (oc & 1) * 64;
    const float* W    = (proj == 0) ? Wth : (proj == 1) ? Weff : Wph;
    const float* bias = (proj == 0) ? bth : (proj == 1) ? beff : bph;

    const int t  = threadIdx.x;
    const int tx = t & 15;
    const int ty = t >> 4;

    float acc[4][4];
#pragma unroll
    for (int u = 0; u < 4; ++u)
#pragma unroll
        for (int v = 0; v < 4; ++v) acc[u][v] = 0.f;

    const float* xb = x + (size_t)b * C_ * N_ + n0;
    for (int k0 = 0; k0 < C_; k0 += 32) {
#pragma unroll
        for (int s = 0; s < 8; ++s) {
            int e = t + 256 * s;
            int kk = e >> 6, col = e & 63;
            Xs[kk][col] = xb[(size_t)(k0 + kk) * N_ + col];
        }
#pragma unroll
        for (int s = 0; s < 8; ++s) {
            int e = t + 256 * s;
            int row = e >> 5, kk = e & 31;
            Ws[row][kk] = W[(orow0 + row) * C_ + k0 + kk];
        }
        __syncthreads();
#pragma unroll
        for (int kk = 0; kk < 32; ++kk) {
            float a[4], xv[4];
#pragma unroll
            for (int u = 0; u < 4; ++u) a[u] = Ws[ty + 16 * u][kk];
#pragma unroll
            for (int v = 0; v < 4; ++v) xv[v] = Xs[kk][tx + 16 * v];
#pragma unroll
            for (int u = 0; u < 4; ++u)
#pragma unroll
                for (int v = 0; v < 4; ++v)
                    acc[u][v] = fmaf(a[u], xv[v], acc[u][v]);
        }
        __syncthreads();
    }

#pragma unroll
    for (int u = 0; u < 4; ++u) {
        const int o = orow0 + ty + 16 * u;
        const float bo = bias[o];
#pragma unroll
        for (int v = 0; v < 4; ++v) {
            const int n = n0 + tx + 16 * v;
            const float val = acc[u][v] + bo;
            if (proj == 2) {
                phi[((size_t)b * IC_ + o) * N_ + n] = val;
            } else {
                float* dst = (proj == 0) ? theta : gW;
                dst[((size_t)b * N_ + n) * IC_ + o] = val;
            }
        }
    }
}

// ---------------------------------------------------------------------------
// hard-row compaction
// ---------------------------------------------------------------------------
__global__ __launch_bounds__(256) void compact_kernel(
    const float* __restrict__ hard_map, int* __restrict__ cnt,
    int* __restrict__ list)
{
    int idx = blockIdx.x * 256 + threadIdx.x;
    if (idx >= B_ * N_) return;
    int b = idx >> 12;
    int n = idx & (N_ - 1);
    if (hard_map[idx] > 0.5f) {
        int p = atomicAdd(&cnt[b], 1);
        list[b * N_ + p] = n;
    }
}

// ---------------------------------------------------------------------------
// score: S[lr][m] = theta[row(lr)] . phi[:,m].  Tile 64r x 128m, K chunk 64.
// grid (N/128 mtiles, qr/64 rtiles). LDS ~50KB -> 3 blocks/CU resident cap.
// ---------------------------------------------------------------------------
__global__ __launch_bounds__(256) void score_kernel(
    const float* __restrict__ theta, const float* __restrict__ phi,
    const int* __restrict__ cnt, const int* __restrict__ list,
    float* __restrict__ S, int b, int r0base)
{
    __shared__ float Th[64][65];    // [r][k]
    __shared__ float Ph[64][132];   // [k][m]
    __shared__ int sIdx[64];

    const int count = cnt[b];
    const int lr0 = blockIdx.y * 64;
    if (r0base + lr0 >= count) return;
    const int m0 = blockIdx.x * 128;
    const int t = threadIdx.x;
    const int tx = t & 15, ty = t >> 4;

    if (t < 64) {
        int gr = r0base + lr0 + t;
        sIdx[t] = (gr < count) ? list[b * N_ + gr] : -1;
    }

    float acc[4][8];
#pragma unroll
    for (int u = 0; u < 4; ++u)
#pragma unroll
        for (int v = 0; v < 8; ++v) acc[u][v] = 0.f;

    for (int kc = 0; kc < IC_; kc += 64) {
        __syncthreads();
        // Th: 64r x 64k (gathered rows)
#pragma unroll
        for (int s = 0; s < 4; ++s) {
            int e4 = t + 256 * s;           // 1024 f4: r=e4>>4, k4=e4&15
            int r = e4 >> 4, k4 = e4 & 15;
            int gr = sIdx[r];
            float4 v = make_float4(0.f, 0.f, 0.f, 0.f);
            if (gr >= 0)
                v = *(const float4*)&theta[((size_t)b * N_ + gr) * IC_ + kc + k4 * 4];
            Th[r][k4 * 4 + 0] = v.x; Th[r][k4 * 4 + 1] = v.y;
            Th[r][k4 * 4 + 2] = v.z; Th[r][k4 * 4 + 3] = v.w;
        }
        // Ph: 64k x 128m
#pragma unroll
        for (int s = 0; s < 8; ++s) {
            int e4 = t + 256 * s;           // 2048 f4: k=e4>>5, m4=e4&31
            int kk = e4 >> 5, m4 = e4 & 31;
            *(float4*)&Ph[kk][m4 * 4] =
                *(const float4*)&phi[((size_t)b * IC_ + kc + kk) * N_ + m0 + m4 * 4];
        }
        __syncthreads();

#pragma unroll 4
        for (int k = 0; k < 64; ++k) {
            float a[4];
#pragma unroll
            for (int u = 0; u < 4; ++u) a[u] = Th[ty * 4 + u][k];
            const float4 p0 = *(const float4*)&Ph[k][tx * 8];
            const float4 p1 = *(const float4*)&Ph[k][tx * 8 + 4];
            const float pm[8] = {p0.x, p0.y, p0.z, p0.w, p1.x, p1.y, p1.z, p1.w};
#pragma unroll
            for (int u = 0; u < 4; ++u)
#pragma unroll
                for (int v = 0; v < 8; ++v)
                    acc[u][v] = fmaf(a[u], pm[v], acc[u][v]);
        }
    }

#pragma unroll
    for (int u = 0; u < 4; ++u) {
        const int lr = lr0 + ty * 4 + u;
        *(float4*)&S[(size_t)lr * N_ + m0 + tx * 8] =
            make_float4(acc[u][0], acc[u][1], acc[u][2], acc[u][3]);
        *(float4*)&S[(size_t)lr * N_ + m0 + tx * 8 + 4] =
            make_float4(acc[u][4], acc[u][5], acc[u][6], acc[u][7]);
    }
}

// ---------------------------------------------------------------------------
// select: per-row exact kth-largest radix select + softmax; writes P in-place
// into S (selected: exp(s-m)*inv, else 0). grid qr blocks.
// ---------------------------------------------------------------------------
__global__ __launch_bounds__(256) void select_kernel(
    float* __restrict__ S, const int* __restrict__ cnt, int b, int r0base)
{
    __shared__ unsigned int sHist[4][256];
    __shared__ unsigned int sWsum[4];
    __shared__ float sRed[8];
    __shared__ unsigned long long sPrefix;
    __shared__ unsigned int sRemain;

    const int lr = blockIdx.x;
    if (r0base + lr >= cnt[b]) return;
    const int t = threadIdx.x, lane = t & 63, wid = t >> 6;

    float4* row = (float4*)(S + (size_t)lr * N_);
    float4 v[4];
#pragma unroll
    for (int q = 0; q < 4; ++q) v[q] = row[t + 256 * q];

    float m = -3.4e38f;
#pragma unroll
    for (int q = 0; q < 4; ++q)
        m = fmaxf(m, fmaxf(fmaxf(v[q].x, v[q].y), fmaxf(v[q].z, v[q].w)));
#pragma unroll
    for (int off = 32; off > 0; off >>= 1) m = fmaxf(m, __shfl_xor(m, off));
    if (lane == 0) sRed[wid] = m;
    __syncthreads();
    m = fmaxf(fmaxf(sRed[0], sRed[1]), fmaxf(sRed[2], sRed[3]));

    unsigned long long prefix = 0ull;
    unsigned int remain = KSEL;
    for (int d = 3; d >= 0; --d) {
        __syncthreads();
#pragma unroll
        for (int w = 0; w < 4; ++w) sHist[w][t] = 0u;
        __syncthreads();
        const float* pv = (const float*)v;
#pragma unroll
        for (int e = 0; e < 16; ++e) {
            unsigned int u = f2u(pv[e]);
            if ((((unsigned long long)u) >> (8 * (d + 1))) == prefix)
                atomicAdd(&sHist[wid][(u >> (8 * d)) & 255u], 1u);
        }
        __syncthreads();
        unsigned int x = sHist[0][t] + sHist[1][t] + sHist[2][t] + sHist[3][t];
        unsigned int own = x;
#pragma unroll
        for (int off = 1; off < 64; off <<= 1) {
            unsigned int y = __shfl_down(x, off);
            if (lane + off < 64) x += y;
        }
        if (lane == 0) sWsum[wid] = x;
        __syncthreads();
        for (int w = wid + 1; w < 4; ++w) x += sWsum[w];
        unsigned int nxt = x - own;        // suffix starting at t+1
        if (x >= remain && nxt < remain) {
            sPrefix = (prefix << 8) | (unsigned long long)t;
            sRemain = remain - nxt;
        }
        __syncthreads();
        prefix = sPrefix;
        remain = sRemain;
    }
    const unsigned int tu = (unsigned int)prefix;

    float z = 0.f, ssel = 0.f;
    const float* pv = (const float*)v;
#pragma unroll
    for (int e = 0; e < 16; ++e) {
        float val = pv[e];
        float ex = expf(val - m);
        z += ex;
        if (f2u(val) >= tu) ssel += ex;
    }
#pragma unroll
    for (int off = 32; off > 0; off >>= 1) {
        z    += __shfl_xor(z, off);
        ssel += __shfl_xor(ssel, off);
    }
    __syncthreads();
    if (lane == 0) { sRed[wid] = z; sRed[4 + wid] = ssel; }
    __syncthreads();
    const float zt = sRed[0] + sRed[1] + sRed[2] + sRed[3];
    const float st = sRed[4] + sRed[5] + sRed[6] + sRed[7];
    const float inv = 1.f / (st + 1e-6f * zt);

    // write P in place
#pragma unroll
    for (int q = 0; q < 4; ++q) {
        float* c = (float*)&v[q];
        float4 p;
        float* pp = (float*)&p;
#pragma unroll
        for (int e = 0; e < 4; ++e)
            pp[e] = (f2u(c[e]) >= tu) ? expf(c[e] - m) * inv : 0.f;
        row[t + 256 * q] = p;
    }
}

// ---------------------------------------------------------------------------
// pv: pure split-K GEMM gc_part[ks][lr][i] = sum_{j in ks*256..} P[lr][j]*gW[j][i]
// grid (qr/64, 16). Tile 64r x 128i, j chunk 64.
// ---------------------------------------------------------------------------
__global__ __launch_bounds__(256) void pv_kernel(
    const float* __restrict__ S, const float* __restrict__ gW,
    const int* __restrict__ cnt, float* __restrict__ gc_part,
    int b, int r0base, int qr)
{
    __shared__ float Pt[64][65];     // [r][j]
    __shared__ float Ws[64][132];    // [j][i]

    const int count = cnt[b];
    const int lr0 = blockIdx.x * 64;
    if (r0base + lr0 >= count) return;
    const int ks = blockIdx.y;
    const int t = threadIdx.x;
    const int tx = t & 15, ty = t >> 4;

    float acc[4][8];
#pragma unroll
    for (int u = 0; u < 4; ++u)
#pragma unroll
        for (int v = 0; v < 8; ++v) acc[u][v] = 0.f;

    for (int jc = ks * 256; jc < ks * 256 + 256; jc += 64) {
        __syncthreads();
        // Pt: 64r x 64j from S (already transformed to P)
#pragma unroll
        for (int s = 0; s < 4; ++s) {
            int e4 = t + 256 * s;
            int r = e4 >> 4, j4 = e4 & 15;
            float4 p = *(const float4*)&S[(size_t)(lr0 + r) * N_ + jc + j4 * 4];
            Pt[r][j4 * 4 + 0] = p.x; Pt[r][j4 * 4 + 1] = p.y;
            Pt[r][j4 * 4 + 2] = p.z; Pt[r][j4 * 4 + 3] = p.w;
        }
        // Ws: 64j x 128i
#pragma unroll
        for (int s = 0; s < 8; ++s) {
            int e4 = t + 256 * s;
            int jj = e4 >> 5, i4 = e4 & 31;
            *(float4*)&Ws[jj][i4 * 4] =
                *(const float4*)&gW[((size_t)b * N_ + jc + jj) * IC_ + i4 * 4];
        }
        __syncthreads();

#pragma unroll 4
        for (int j = 0; j < 64; ++j) {
            float a[4];
#pragma unroll
            for (int u = 0; u < 4; ++u) a[u] = Pt[ty * 4 + u][j];
            const float4 w0 = *(const float4*)&Ws[j][tx * 8];
            const float4 w1 = *(const float4*)&Ws[j][tx * 8 + 4];
            const float wm[8] = {w0.x, w0.y, w0.z, w0.w, w1.x, w1.y, w1.z, w1.w};
#pragma unroll
            for (int u = 0; u < 4; ++u)
#pragma unroll
                for (int v = 0; v < 8; ++v)
                    acc[u][v] = fmaf(a[u], wm[v], acc[u][v]);
        }
    }

#pragma unroll
    for (int u = 0; u < 4; ++u) {
        const int lr = lr0 + ty * 4 + u;
        *(float4*)&gc_part[((size_t)ks * qr + lr) * IC_ + tx * 8] =
            make_float4(acc[u][0], acc[u][1], acc[u][2], acc[u][3]);
        *(float4*)&gc_part[((size_t)ks * qr + lr) * IC_ + tx * 8 + 4] =
            make_float4(acc[u][4], acc[u][5], acc[u][6], acc[u][7]);
    }
}

// ---------------------------------------------------------------------------
// reduce split-K partials, ReLU, scatter to gc[b][n][i]
// ---------------------------------------------------------------------------
__global__ __launch_bounds__(256) void scatter_kernel(
    const float* __restrict__ gc_part, const int* __restrict__ cnt,
    const int* __restrict__ list, float* __restrict__ gc,
    int b, int r0base, int qr)
{
    int idx = blockIdx.x * 256 + threadIdx.x;
    int lr = idx >> 7, i = idx & 127;
    if (r0base + lr >= cnt[b]) return;
    float v = 0.f;
#pragma unroll
    for (int ks = 0; ks < 16; ++ks)
        v += gc_part[((size_t)ks * qr + lr) * IC_ + i];
    int n = list[b * N_ + r0base + lr];
    gc[((size_t)b * N_ + n) * IC_ + i] = fmaxf(v, 0.f);
}

// ---------------------------------------------------------------------------
// y[b,c,n] = Wout[c,:] . gc[b,n,:] + bout[c].  Tile 64c x 64n, K chunk 32.
// grid (N/64, C/64, B) = 512 blocks, acc 4x4/thread.
// ---------------------------------------------------------------------------
__global__ __launch_bounds__(256) void y_kernel(
    const float* __restrict__ gc, const float* __restrict__ Wout,
    const float* __restrict__ bout, float* __restrict__ y)
{
    __shared__ float Wt[64][33];   // [c][k]
    __shared__ float Gt[32][68];   // [k][n]
    const int n0 = blockIdx.x * 64;
    const int c0 = blockIdx.y * 64;
    const int b  = blockIdx.z;
    const int t = threadIdx.x;
    const int tx = t & 15, ty = t >> 4;

    float acc[4][4];
#pragma unroll
    for (int u = 0; u < 4; ++u)
#pragma unroll
        for (int v = 0; v < 4; ++v) acc[u][v] = 0.f;

    for (int kc = 0; kc < IC_; kc += 32) {
        __syncthreads();
        // Wt: 64c x 32k
#pragma unroll
        for (int s = 0; s < 2; ++s) {
            int e4 = t + 256 * s;            // 512 f4: c=e4>>3, k4=e4&7
            int c = e4 >> 3, k4 = e4 & 7;
            float4 w = *(const float4*)&Wout[(size_t)(c0 + c) * IC_ + kc + k4 * 4];
            Wt[c][k4 * 4 + 0] = w.x; Wt[c][k4 * 4 + 1] = w.y;
            Wt[c][k4 * 4 + 2] = w.z; Wt[c][k4 * 4 + 3] = w.w;
        }
        // Gt: 32k x 64n (transposed from gc [n][i])
#pragma unroll
        for (int s = 0; s < 2; ++s) {
            int e4 = t + 256 * s;            // 512 f4: nn=e4>>3, k4=e4&7
            int nn = e4 >> 3, k4 = e4 & 7;
            float4 g = *(const float4*)&gc[((size_t)b * N_ + n0 + nn) * IC_ + kc + k4 * 4];
            Gt[k4 * 4 + 0][nn] = g.x; Gt[k4 * 4 + 1][nn] = g.y;
            Gt[k4 * 4 + 2][nn] = g.z; Gt[k4 * 4 + 3][nn] = g.w;
        }
        __syncthreads();

#pragma unroll 4
        for (int k = 0; k < 32; ++k) {
            float a[4];
#pragma unroll
            for (int u = 0; u < 4; ++u) a[u] = Wt[ty * 4 + u][k];
            const float4 g4 = *(const float4*)&Gt[k][tx * 4];
            const float gm[4] = {g4.x, g4.y, g4.z, g4.w};
#pragma unroll
            for (int u = 0; u < 4; ++u)
#pragma unroll
                for (int v = 0; v < 4; ++v)
                    acc[u][v] = fmaf(a[u], gm[v], acc[u][v]);
        }
    }

#pragma unroll
    for (int u = 0; u < 4; ++u) {
        const int c = c0 + ty * 4 + u;
        const float bo = bout[c];
        *(float4*)&y[((size_t)b * C_ + c) * N_ + n0 + tx * 4] =
            make_float4(acc[u][0] + bo, acc[u][1] + bo,
                        acc[u][2] + bo, acc[u][3] + bo);
    }
}

// ---------------------------------------------------------------------------
// BatchNorm stats per channel
// ---------------------------------------------------------------------------
__global__ __launch_bounds__(256) void bn_stats_kernel(
    const float* __restrict__ y, float* __restrict__ mean,
    float* __restrict__ rsig)
{
    __shared__ float sr[8];
    const int c = blockIdx.x, t = threadIdx.x;
    const int lane = t & 63, wid = t >> 6;
    float s = 0.f, ss = 0.f;
    for (int b = 0; b < B_; ++b) {
        const float* yr = y + ((size_t)b * C_ + c) * N_;
        for (int n = t; n < N_; n += 256) {
            float v = yr[n];
            s += v; ss = fmaf(v, v, ss);
        }
    }
#pragma unroll
    for (int off = 32; off > 0; off >>= 1) {
        s  += __shfl_xor(s, off);
        ss += __shfl_xor(ss, off);
    }
    if (lane == 0) { sr[wid] = s; sr[4 + wid] = ss; }
    __syncthreads();
    if (t == 0) {
        float st  = sr[0] + sr[1] + sr[2] + sr[3];
        float sst = sr[4] + sr[5] + sr[6] + sr[7];
        float mu  = st / (float)(B_ * N_);
        float var = sst / (float)(B_ * N_) - mu * mu;
        mean[c] = mu;
        rsig[c] = rsqrtf(var + 1e-5f);
    }
}

// ---------------------------------------------------------------------------
// out = x + gamma*(y-mean)*rsig + beta
// ---------------------------------------------------------------------------
__global__ __launch_bounds__(256) void final_kernel(
    const float* __restrict__ x, const float* __restrict__ y,
    const float* __restrict__ mean, const float* __restrict__ rsig,
    const float* __restrict__ gamma, const float* __restrict__ beta,
    float* __restrict__ out)
{
    int idx = blockIdx.x * 256 + threadIdx.x;
    if (idx >= B_ * C_ * N_) return;
    int c = (idx >> 12) & (C_ - 1);
    out[idx] = x[idx] + fmaf(gamma[c], (y[idx] - mean[c]) * rsig[c], beta[c]);
}

extern "C" void kernel_launch(void* const* d_in, const int* in_sizes, int n_in,
                              void* d_out, int out_size, void* d_ws, size_t ws_size,
                              hipStream_t stream)
{
    const float* x     = (const float*)d_in[0];
    const float* hard  = (const float*)d_in[1];
    const float* Wg    = (const float*)d_in[2];
    const float* bg    = (const float*)d_in[3];
    const float* Wth   = (const float*)d_in[4];
    const float* bth   = (const float*)d_in[5];
    const float* Wph   = (const float*)d_in[6];
    const float* bph   = (const float*)d_in[7];
    const float* Wgcn  = (const float*)d_in[8];
    const float* Wout  = (const float*)d_in[9];
    const float* bout  = (const float*)d_in[10];
    const float* gamma = (const float*)d_in[11];
    const float* beta  = (const float*)d_in[12];
    float* out = (float*)d_out;
    float* ws  = (float*)d_ws;

    float* theta = ws + OFF_THETA;
    float* phi   = ws + OFF_PHI;
    float* gW    = ws + OFF_GW;
    float* gc    = ws + OFF_GC;
    float* y     = ws + OFF_Y;
    float* Weff  = ws + OFF_WEFF;
    float* beff  = ws + OFF_BEFF;
    float* mean  = ws + OFF_MEAN;
    float* rsig  = ws + OFF_RSIG;
    int*   cnt   = (int*)(ws + OFF_CNT);
    int*   list  = (int*)(ws + OFF_LIST);

    // runtime-adaptive row-block size: pick largest that fits the workspace
    const size_t wsf = ws_size / sizeof(float);
    int qr = 1024;
    if (wsf >= OFF_DYN + 25165824u)       qr = 4096;  // S 16M + gc_part 8M
    else if (wsf >= OFF_DYN + 12582912u)  qr = 2048;  // S 8M  + gc_part 4M
    float* S = ws + OFF_DYN;
    float* gc_part = (qr == 1024) ? out : S + (size_t)qr * N_;
    // (qr==1024: d_out (2M floats) used as split-K scratch, fully overwritten
    //  by final_kernel at the end.)

    hipMemsetAsync(cnt, 0, 2 * sizeof(int), stream);
    hipMemsetAsync(gc, 0, (size_t)B_ * N_ * IC_ * sizeof(float), stream);

    weff_kernel<<<dim3(IC_), 256, 0, stream>>>(Wg, bg, Wgcn, Weff, beff);
    proj_kernel<<<dim3(6, N_ / 64, B_), 256, 0, stream>>>(
        x, Wth, bth, Weff, beff, Wph, bph, theta, gW, phi);
    compact_kernel<<<dim3(B_ * N_ / 256), 256, 0, stream>>>(hard, cnt, list);

    for (int b = 0; b < B_; ++b) {
        for (int r0 = 0; r0 < N_; r0 += qr) {
            score_kernel<<<dim3(N_ / 128, qr / 64), 256, 0, stream>>>(
                theta, phi, cnt, list, S, b, r0);
            select_kernel<<<dim3(qr), 256, 0, stream>>>(S, cnt, b, r0);
            pv_kernel<<<dim3(qr / 64, 16), 256, 0, stream>>>(
                S, gW, cnt, gc_part, b, r0, qr);
            scatter_kernel<<<dim3(qr / 2), 256, 0, stream>>>(
                gc_part, cnt, list, gc, b, r0, qr);
        }
    }

    y_kernel<<<dim3(N_ / 64, C_ / 64, B_), 256, 0, stream>>>(gc, Wout, bout, y);
    bn_stats_kernel<<<dim3(C_), 256, 0, stream>>>(y, mean, rsig);
    final_kernel<<<dim3(B_ * C_ * N_ / 256), 256, 0, stream>>>(
        x, y, mean, rsig, gamma, beta, out);
}

// Round 8
// 336.512 us; speedup vs baseline: 1.1748x; 1.1748x over previous
//
#include <hip/hip_runtime.h>

#define B_ 2
#define C_ 256
#define IC_ 128
#define N_ 4096
#define KSEL 2048
#define QR 1024

// workspace offsets (floats) — total ~35.8 MB
#define OFF_GC    0u
#define OFF_Y     1048576u
#define OFF_WEFF  3145728u
#define OFF_BEFF  3178496u
#define OFF_MEAN  3178624u
#define OFF_RSIG  3178880u
#define OFF_CNT   3179136u
#define OFF_LIST  3179200u
#define OFF_THB   3187456u   // theta f16 [B][N][IC]   (512K floats)
#define OFF_PHB   3711744u   // phi   f16 [B][N][IC]   (n-major!)
#define OFF_GWT   4236032u   // gW^T  f16 [B][IC][N]
#define OFF_S     4760320u   // S fp32 [QR][N]; P f16 written in-place

typedef __attribute__((ext_vector_type(8))) _Float16 f16x8;
typedef __attribute__((ext_vector_type(4))) float f32x4;

__device__ __forceinline__ unsigned int f2u(float f) {
    unsigned int u = __float_as_uint(f);
    return (u & 0x80000000u) ? ~u : (u | 0x80000000u);
}
__device__ __forceinline__ unsigned short f2h(float f) {
    union { _Float16 h; unsigned short u; } cv;
    cv.h = (_Float16)f;          // RTN-even hardware convert
    return cv.u;
}

// ---------------------------------------------------------------------------
// Weff[o][c] = sum_i Wgcn[i][o] * Wg[i][c];  beff[o] = sum_i Wgcn[i][o]*bg[i]
// ---------------------------------------------------------------------------
__global__ __launch_bounds__(256) void weff_kernel(
    const float* __restrict__ Wg, const float* __restrict__ bg,
    const float* __restrict__ Wgcn, float* __restrict__ Weff,
    float* __restrict__ beff)
{
    const int o = blockIdx.x, c = threadIdx.x;
    float acc = 0.f;
    for (int i = 0; i < IC_; ++i)
        acc = fmaf(Wgcn[i * IC_ + o], Wg[i * C_ + c], acc);
    Weff[o * C_ + c] = acc;
    if (c == 0) {
        float bacc = 0.f;
        for (int i = 0; i < IC_; ++i)
            bacc = fmaf(Wgcn[i * IC_ + o], bg[i], bacc);
        beff[o] = bacc;
    }
}

// ---------------------------------------------------------------------------
// Projections (fp32 GEMM, f16 outputs):
//  proj0: theta -> thetaH [b][n][o] ; proj1: gW -> gWT [b][o][n] ;
//  proj2: phi   -> phiH   [b][n][o]
// ---------------------------------------------------------------------------
__global__ __launch_bounds__(256) void proj_kernel(
    const float* __restrict__ x,
    const float* __restrict__ Wth, const float* __restrict__ bth,
    const float* __restrict__ Weff, const float* __restrict__ beff,
    const float* __restrict__ Wph, const float* __restrict__ bph,
    unsigned short* __restrict__ thetaH, unsigned short* __restrict__ gWT,
    unsigned short* __restrict__ phiH)
{
    __shared__ float Xs[32][65];
    __shared__ float Ws[64][33];
    const int oc    = blockIdx.x;
    const int n0    = blockIdx.y * 64;
    const int b     = blockIdx.z;
    const int proj  = oc >> 1;
    const int orow0 = (oc & 1) * 64;
    const float* W    = (proj == 0) ? Wth : (proj == 1) ? Weff : Wph;
    const float* bias = (proj == 0) ? bth : (proj == 1) ? beff : bph;

    const int t  = threadIdx.x;
    const int tx = t & 15;
    const int ty = t >> 4;

    float acc[4][4];
#pragma unroll
    for (int u = 0; u < 4; ++u)
#pragma unroll
        for (int v = 0; v < 4; ++v) acc[u][v] = 0.f;

    const float* xb = x + (size_t)b * C_ * N_ + n0;
    for (int k0 = 0; k0 < C_; k0 += 32) {
#pragma unroll
        for (int s = 0; s < 8; ++s) {
            int e = t + 256 * s;
            int kk = e >> 6, col = e & 63;
            Xs[kk][col] = xb[(size_t)(k0 + kk) * N_ + col];
        }
#pragma unroll
        for (int s = 0; s < 8; ++s) {
            int e = t + 256 * s;
            int row = e >> 5, kk = e & 31;
            Ws[row][kk] = W[(orow0 + row) * C_ + k0 + kk];
        }
        __syncthreads();
#pragma unroll
        for (int kk = 0; kk < 32; ++kk) {
            float a[4], xv[4];
#pragma unroll
            for (int u = 0; u < 4; ++u) a[u] = Ws[ty + 16 * u][kk];
#pragma unroll
            for (int v = 0; v < 4; ++v) xv[v] = Xs[kk][tx + 16 * v];
#pragma unroll
            for (int u = 0; u < 4; ++u)
#pragma unroll
                for (int v = 0; v < 4; ++v)
                    acc[u][v] = fmaf(a[u], xv[v], acc[u][v]);
        }
        __syncthreads();
    }

#pragma unroll
    for (int u = 0; u < 4; ++u) {
        const int o = orow0 + ty + 16 * u;
        const float bo = bias[o];
#pragma unroll
        for (int v = 0; v < 4; ++v) {
            const int n = n0 + tx + 16 * v;
            const unsigned short h = f2h(acc[u][v] + bo);
            if (proj == 0)
                thetaH[((size_t)b * N_ + n) * IC_ + o] = h;
            else if (proj == 1)
                gWT[((size_t)b * IC_ + o) * N_ + n] = h;
            else
                phiH[((size_t)b * N_ + n) * IC_ + o] = h;
        }
    }
}

// ---------------------------------------------------------------------------
// hard-row compaction
// ---------------------------------------------------------------------------
__global__ __launch_bounds__(256) void compact_kernel(
    const float* __restrict__ hard_map, int* __restrict__ cnt,
    int* __restrict__ list)
{
    int idx = blockIdx.x * 256 + threadIdx.x;
    if (idx >= B_ * N_) return;
    int b = idx >> 12;
    int n = idx & (N_ - 1);
    if (hard_map[idx] > 0.5f) {
        int p = atomicAdd(&cnt[b], 1);
        list[b * N_ + p] = n;
    }
}

// ---------------------------------------------------------------------------
// score (MFMA f16): S[lr][m] = theta_row(lr) . phi[:,m], fp32 out.
// 128r x 128m tile, 4 waves, 16 mfma-tiles/wave, K=128 in 4 steps.
// grid (N/128, QR/128)
// ---------------------------------------------------------------------------
__global__ __launch_bounds__(256) void score_kernel(
    const unsigned short* __restrict__ thetaH,
    const unsigned short* __restrict__ phiH,
    const int* __restrict__ cnt, const int* __restrict__ list,
    float* __restrict__ S, int b, int r0base)
{
    __shared__ unsigned short Th[128][136];   // [r][k], +8 pad
    __shared__ unsigned short Ph[128][136];   // [m][k], +8 pad
    __shared__ int sIdx[128];

    const int count = cnt[b];
    const int lr0 = blockIdx.y * 128;
    if (r0base + lr0 >= count) return;
    const int m0 = blockIdx.x * 128;
    const int t = threadIdx.x;
    const int w = t >> 6, lane = t & 63;

    if (t < 128) {
        int gr = r0base + lr0 + t;
        sIdx[t] = (gr < count) ? list[b * N_ + gr] : -1;
    }
    __syncthreads();

    // stage theta (gathered rows) and phi rows, 16B loads
#pragma unroll
    for (int s = 0; s < 8; ++s) {
        int e4 = t + 256 * s;                 // 2048 x 16B
        int r = e4 >> 4, k4 = e4 & 15;
        int gr = sIdx[r];
        float4 v = make_float4(0.f, 0.f, 0.f, 0.f);
        if (gr >= 0)
            v = *(const float4*)&thetaH[((size_t)b * N_ + gr) * IC_ + k4 * 8];
        *(float4*)&Th[r][k4 * 8] = v;
    }
#pragma unroll
    for (int s = 0; s < 8; ++s) {
        int e4 = t + 256 * s;
        int r = e4 >> 4, k4 = e4 & 15;
        *(float4*)&Ph[r][k4 * 8] =
            *(const float4*)&phiH[((size_t)b * N_ + m0 + r) * IC_ + k4 * 8];
    }
    __syncthreads();

    const int wr = (w >> 1) * 64, wm = (w & 1) * 64;
    const int lrow = lane & 15, lk = (lane >> 4) * 8;

    f32x4 acc[4][4];
#pragma unroll
    for (int u = 0; u < 4; ++u)
#pragma unroll
        for (int v = 0; v < 4; ++v) acc[u][v] = (f32x4)(0.f);

#pragma unroll
    for (int ks = 0; ks < 4; ++ks) {
        const int kk = ks * 32 + lk;
        f16x8 af[4], bf_[4];
#pragma unroll
        for (int u = 0; u < 4; ++u)
            af[u] = *(const f16x8*)&Th[wr + u * 16 + lrow][kk];
#pragma unroll
        for (int v = 0; v < 4; ++v)
            bf_[v] = *(const f16x8*)&Ph[wm + v * 16 + lrow][kk];
#pragma unroll
        for (int u = 0; u < 4; ++u)
#pragma unroll
            for (int v = 0; v < 4; ++v)
                acc[u][v] = __builtin_amdgcn_mfma_f32_16x16x32_f16(
                    af[u], bf_[v], acc[u][v], 0, 0, 0);
    }

    const int crow = (lane >> 4) * 4;
#pragma unroll
    for (int u = 0; u < 4; ++u) {
#pragma unroll
        for (int v = 0; v < 4; ++v) {
            const int row = lr0 + wr + u * 16 + crow;
            const int col = m0 + wm + v * 16 + lrow;
#pragma unroll
            for (int r = 0; r < 4; ++r)
                S[(size_t)(row + r) * N_ + col] = acc[u][v][r];
        }
    }
}

// ---------------------------------------------------------------------------
// select: exact kth-largest radix select + softmax on fp32 S row;
// writes P as f16 IN-PLACE over the row. grid QR blocks.
// ---------------------------------------------------------------------------
__global__ __launch_bounds__(256) void select_kernel(
    float* __restrict__ S, const int* __restrict__ cnt, int b, int r0base)
{
    __shared__ unsigned int sHist[4][256];
    __shared__ unsigned int sWsum[4];
    __shared__ float sRed[8];
    __shared__ unsigned long long sPrefix;
    __shared__ unsigned int sRemain;

    const int lr = blockIdx.x;
    if (r0base + lr >= cnt[b]) return;
    const int t = threadIdx.x, lane = t & 63, wid = t >> 6;

    float4* row = (float4*)(S + (size_t)lr * N_);
    float4 v[4];
#pragma unroll
    for (int q = 0; q < 4; ++q) v[q] = row[t + 256 * q];

    float m = -3.4e38f;
#pragma unroll
    for (int q = 0; q < 4; ++q)
        m = fmaxf(m, fmaxf(fmaxf(v[q].x, v[q].y), fmaxf(v[q].z, v[q].w)));
#pragma unroll
    for (int off = 32; off > 0; off >>= 1) m = fmaxf(m, __shfl_xor(m, off));
    if (lane == 0) sRed[wid] = m;
    __syncthreads();
    m = fmaxf(fmaxf(sRed[0], sRed[1]), fmaxf(sRed[2], sRed[3]));

    unsigned long long prefix = 0ull;
    unsigned int remain = KSEL;
    for (int d = 3; d >= 0; --d) {
        __syncthreads();
#pragma unroll
        for (int ww = 0; ww < 4; ++ww) sHist[ww][t] = 0u;
        __syncthreads();
        const float* pv = (const float*)v;
#pragma unroll
        for (int e = 0; e < 16; ++e) {
            unsigned int u = f2u(pv[e]);
            if ((((unsigned long long)u) >> (8 * (d + 1))) == prefix)
                atomicAdd(&sHist[wid][(u >> (8 * d)) & 255u], 1u);
        }
        __syncthreads();
        unsigned int x = sHist[0][t] + sHist[1][t] + sHist[2][t] + sHist[3][t];
        unsigned int own = x;
#pragma unroll
        for (int off = 1; off < 64; off <<= 1) {
            unsigned int y = __shfl_down(x, off);
            if (lane + off < 64) x += y;
        }
        if (lane == 0) sWsum[wid] = x;
        __syncthreads();
        for (int ww = wid + 1; ww < 4; ++ww) x += sWsum[ww];
        unsigned int nxt = x - own;
        if (x >= remain && nxt < remain) {
            sPrefix = (prefix << 8) | (unsigned long long)t;
            sRemain = remain - nxt;
        }
        __syncthreads();
        prefix = sPrefix;
        remain = sRemain;
    }
    const unsigned int tu = (unsigned int)prefix;

    float z = 0.f, ssel = 0.f;
    const float* pv = (const float*)v;
#pragma unroll
    for (int e = 0; e < 16; ++e) {
        float val = pv[e];
        float ex = expf(val - m);
        z += ex;
        if (f2u(val) >= tu) ssel += ex;
    }
#pragma unroll
    for (int off = 32; off > 0; off >>= 1) {
        z    += __shfl_xor(z, off);
        ssel += __shfl_xor(ssel, off);
    }
    __syncthreads();
    if (lane == 0) { sRed[wid] = z; sRed[4 + wid] = ssel; }
    __syncthreads();
    const float zt = sRed[0] + sRed[1] + sRed[2] + sRed[3];
    const float st = sRed[4] + sRed[5] + sRed[6] + sRed[7];
    const float inv = 1.f / (st + 1e-6f * zt);

    // write P (f16) in place over the fp32 row
    unsigned short* prow = (unsigned short*)(S + (size_t)lr * N_);
#pragma unroll
    for (int q = 0; q < 4; ++q) {
        const float* c = (const float*)&v[q];
        ushort4 p;
        p.x = (f2u(c[0]) >= tu) ? f2h(expf(c[0] - m) * inv) : (unsigned short)0;
        p.y = (f2u(c[1]) >= tu) ? f2h(expf(c[1] - m) * inv) : (unsigned short)0;
        p.z = (f2u(c[2]) >= tu) ? f2h(expf(c[2] - m) * inv) : (unsigned short)0;
        p.w = (f2u(c[3]) >= tu) ? f2h(expf(c[3] - m) * inv) : (unsigned short)0;
        *(ushort4*)&prow[4 * (t + 256 * q)] = p;
    }
}

// ---------------------------------------------------------------------------
// pv (MFMA f16, split-K): gc_part[ks][lr][i] += over j in [ks*256, ks*256+256)
// of P[lr][j] * gWT[i][j].  64r x 128i tile, j chunk 64. grid (QR/64, 16)
// ---------------------------------------------------------------------------
__global__ __launch_bounds__(256) void pv_kernel(
    const float* __restrict__ S, const unsigned short* __restrict__ gWT,
    const int* __restrict__ cnt, float* __restrict__ gc_part,
    int b, int r0base)
{
    __shared__ unsigned short Pt[64][72];    // [r][j], +8 pad
    __shared__ unsigned short Gt[128][72];   // [i][j], +8 pad

    const int count = cnt[b];
    const int lr0 = blockIdx.x * 64;
    if (r0base + lr0 >= count) return;
    const int ks = blockIdx.y;
    const int t = threadIdx.x;
    const int w = t >> 6, lane = t & 63;
    const int lrow = lane & 15, lk = (lane >> 4) * 8;
    const int wr0 = (w >> 1) * 32, ic0 = (w & 1) * 64;

    f32x4 acc[2][4];
#pragma unroll
    for (int u = 0; u < 2; ++u)
#pragma unroll
        for (int v = 0; v < 4; ++v) acc[u][v] = (f32x4)(0.f);

    for (int jc = ks * 256; jc < ks * 256 + 256; jc += 64) {
        __syncthreads();
        // P tile: 64 rows x 64 f16
#pragma unroll
        for (int s = 0; s < 2; ++s) {
            int e4 = t + 256 * s;             // 512 x 16B
            int r = e4 >> 3, k4 = e4 & 7;
            const unsigned short* prow =
                (const unsigned short*)(S + (size_t)(lr0 + r) * N_);
            *(float4*)&Pt[r][k4 * 8] = *(const float4*)&prow[jc + k4 * 8];
        }
        // gWT tile: 128 i x 64 f16
#pragma unroll
        for (int s = 0; s < 4; ++s) {
            int e4 = t + 256 * s;             // 1024 x 16B
            int i = e4 >> 3, k4 = e4 & 7;
            *(float4*)&Gt[i][k4 * 8] =
                *(const float4*)&gWT[((size_t)b * IC_ + i) * N_ + jc + k4 * 8];
        }
        __syncthreads();

#pragma unroll
        for (int kstep = 0; kstep < 2; ++kstep) {
            const int kk = kstep * 32 + lk;
            f16x8 af[2], bf_[4];
#pragma unroll
            for (int u = 0; u < 2; ++u)
                af[u] = *(const f16x8*)&Pt[wr0 + u * 16 + lrow][kk];
#pragma unroll
            for (int v = 0; v < 4; ++v)
                bf_[v] = *(const f16x8*)&Gt[ic0 + v * 16 + lrow][kk];
#pragma unroll
            for (int u = 0; u < 2; ++u)
#pragma unroll
                for (int v = 0; v < 4; ++v)
                    acc[u][v] = __builtin_amdgcn_mfma_f32_16x16x32_f16(
                        af[u], bf_[v], acc[u][v], 0, 0, 0);
        }
    }

    const int crow = (lane >> 4) * 4;
#pragma unroll
    for (int u = 0; u < 2; ++u) {
#pragma unroll
        for (int v = 0; v < 4; ++v) {
            const int row = lr0 + wr0 + u * 16 + crow;
            const int i = ic0 + v * 16 + lrow;
#pragma unroll
            for (int r = 0; r < 4; ++r)
                gc_part[((size_t)ks * QR + row + r) * IC_ + i] = acc[u][v][r];
        }
    }
}

// ---------------------------------------------------------------------------
// reduce split-K partials, ReLU, scatter to gc[b][n][i]
// ---------------------------------------------------------------------------
__global__ __launch_bounds__(256) void scatter_kernel(
    const float* __restrict__ gc_part, const int* __restrict__ cnt,
    const int* __restrict__ list, float* __restrict__ gc, int b, int r0base)
{
    int idx = blockIdx.x * 256 + threadIdx.x;
    int lr = idx >> 7, i = idx & 127;
    if (r0base + lr >= cnt[b]) return;
    float v = 0.f;
#pragma unroll
    for (int ks = 0; ks < 16; ++ks)
        v += gc_part[((size_t)ks * QR + lr) * IC_ + i];
    int n = list[b * N_ + r0base + lr];
    gc[((size_t)b * N_ + n) * IC_ + i] = fmaxf(v, 0.f);
}

// ---------------------------------------------------------------------------
// y[b,c,n] = Wout[c,:] . gc[b,n,:] + bout[c].  64c x 64n tiles.
// ---------------------------------------------------------------------------
__global__ __launch_bounds__(256) void y_kernel(
    const float* __restrict__ gc, const float* __restrict__ Wout,
    const float* __restrict__ bout, float* __restrict__ y)
{
    __shared__ float Wt[64][33];
    __shared__ float Gt[32][68];
    const int n0 = blockIdx.x * 64;
    const int c0 = blockIdx.y * 64;
    const int b  = blockIdx.z;
    const int t = threadIdx.x;
    const int tx = t & 15, ty = t >> 4;

    float acc[4][4];
#pragma unroll
    for (int u = 0; u < 4; ++u)
#pragma unroll
        for (int v = 0; v < 4; ++v) acc[u][v] = 0.f;

    for (int kc = 0; kc < IC_; kc += 32) {
        __syncthreads();
#pragma unroll
        for (int s = 0; s < 2; ++s) {
            int e4 = t + 256 * s;
            int c = e4 >> 3, k4 = e4 & 7;
            float4 ww = *(const float4*)&Wout[(size_t)(c0 + c) * IC_ + kc + k4 * 4];
            Wt[c][k4 * 4 + 0] = ww.x; Wt[c][k4 * 4 + 1] = ww.y;
            Wt[c][k4 * 4 + 2] = ww.z; Wt[c][k4 * 4 + 3] = ww.w;
        }
#pragma unroll
        for (int s = 0; s < 2; ++s) {
            int e4 = t + 256 * s;
            int nn = e4 >> 3, k4 = e4 & 7;
            float4 g = *(const float4*)&gc[((size_t)b * N_ + n0 + nn) * IC_ + kc + k4 * 4];
            Gt[k4 * 4 + 0][nn] = g.x; Gt[k4 * 4 + 1][nn] = g.y;
            Gt[k4 * 4 + 2][nn] = g.z; Gt[k4 * 4 + 3][nn] = g.w;
        }
        __syncthreads();

#pragma unroll 4
        for (int k = 0; k < 32; ++k) {
            float a[4];
#pragma unroll
            for (int u = 0; u < 4; ++u) a[u] = Wt[ty * 4 + u][k];
            const float4 g4 = *(const float4*)&Gt[k][tx * 4];
            const float gm[4] = {g4.x, g4.y, g4.z, g4.w};
#pragma unroll
            for (int u = 0; u < 4; ++u)
#pragma unroll
                for (int v = 0; v < 4; ++v)
                    acc[u][v] = fmaf(a[u], gm[v], acc[u][v]);
        }
    }

#pragma unroll
    for (int u = 0; u < 4; ++u) {
        const int c = c0 + ty * 4 + u;
        const float bo = bout[c];
        *(float4*)&y[((size_t)b * C_ + c) * N_ + n0 + tx * 4] =
            make_float4(acc[u][0] + bo, acc[u][1] + bo,
                        acc[u][2] + bo, acc[u][3] + bo);
    }
}

// ---------------------------------------------------------------------------
// BatchNorm stats per channel
// ---------------------------------------------------------------------------
__global__ __launch_bounds__(256) void bn_stats_kernel(
    const float* __restrict__ y, float* __restrict__ mean,
    float* __restrict__ rsig)
{
    __shared__ float sr[8];
    const int c = blockIdx.x, t = threadIdx.x;
    const int lane = t & 63, wid = t >> 6;
    float s = 0.f, ss = 0.f;
    for (int b = 0; b < B_; ++b) {
        const float* yr = y + ((size_t)b * C_ + c) * N_;
        for (int n = t; n < N_; n += 256) {
            float v = yr[n];
            s += v; ss = fmaf(v, v, ss);
        }
    }
#pragma unroll
    for (int off = 32; off > 0; off >>= 1) {
        s  += __shfl_xor(s, off);
        ss += __shfl_xor(ss, off);
    }
    if (lane == 0) { sr[wid] = s; sr[4 + wid] = ss; }
    __syncthreads();
    if (t == 0) {
        float st  = sr[0] + sr[1] + sr[2] + sr[3];
        float sst = sr[4] + sr[5] + sr[6] + sr[7];
        float mu  = st / (float)(B_ * N_);
        float var = sst / (float)(B_ * N_) - mu * mu;
        mean[c] = mu;
        rsig[c] = rsqrtf(var + 1e-5f);
    }
}

// ---------------------------------------------------------------------------
// out = x + gamma*(y-mean)*rsig + beta
// ---------------------------------------------------------------------------
__global__ __launch_bounds__(256) void final_kernel(
    const float* __restrict__ x, const float* __restrict__ y,
    const float* __restrict__ mean, const float* __restrict__ rsig,
    const float* __restrict__ gamma, const float* __restrict__ beta,
    float* __restrict__ out)
{
    int idx = blockIdx.x * 256 + threadIdx.x;
    if (idx >= B_ * C_ * N_) return;
    int c = (idx >> 12) & (C_ - 1);
    out[idx] = x[idx] + fmaf(gamma[c], (y[idx] - mean[c]) * rsig[c], beta[c]);
}

extern "C" void kernel_launch(void* const* d_in, const int* in_sizes, int n_in,
                              void* d_out, int out_size, void* d_ws, size_t ws_size,
                              hipStream_t stream)
{
    const float* x     = (const float*)d_in[0];
    const float* hard  = (const float*)d_in[1];
    const float* Wg    = (const float*)d_in[2];
    const float* bg    = (const float*)d_in[3];
    const float* Wth   = (const float*)d_in[4];
    const float* bth   = (const float*)d_in[5];
    const float* Wph   = (const float*)d_in[6];
    const float* bph   = (const float*)d_in[7];
    const float* Wgcn  = (const float*)d_in[8];
    const float* Wout  = (const float*)d_in[9];
    const float* bout  = (const float*)d_in[10];
    const float* gamma = (const float*)d_in[11];
    const float* beta  = (const float*)d_in[12];
    float* out = (float*)d_out;
    float* ws  = (float*)d_ws;

    float* gc    = ws + OFF_GC;
    float* y     = ws + OFF_Y;
    float* Weff  = ws + OFF_WEFF;
    float* beff  = ws + OFF_BEFF;
    float* mean  = ws + OFF_MEAN;
    float* rsig  = ws + OFF_RSIG;
    int*   cnt   = (int*)(ws + OFF_CNT);
    int*   list  = (int*)(ws + OFF_LIST);
    unsigned short* thetaH = (unsigned short*)(ws + OFF_THB);
    unsigned short* phiH   = (unsigned short*)(ws + OFF_PHB);
    unsigned short* gWT    = (unsigned short*)(ws + OFF_GWT);
    float* S = ws + OFF_S;
    float* gc_part = out;   // d_out (8 MB = 16*QR*IC_*4) as split-K scratch;
                            // fully overwritten by final_kernel at the end.

    hipMemsetAsync(cnt, 0, 2 * sizeof(int), stream);
    hipMemsetAsync(gc, 0, (size_t)B_ * N_ * IC_ * sizeof(float), stream);

    weff_kernel<<<dim3(IC_), 256, 0, stream>>>(Wg, bg, Wgcn, Weff, beff);
    proj_kernel<<<dim3(6, N_ / 64, B_), 256, 0, stream>>>(
        x, Wth, bth, Weff, beff, Wph, bph, thetaH, gWT, phiH);
    compact_kernel<<<dim3(B_ * N_ / 256), 256, 0, stream>>>(hard, cnt, list);

    for (int b = 0; b < B_; ++b) {
        for (int r0 = 0; r0 < N_; r0 += QR) {
            score_kernel<<<dim3(N_ / 128, QR / 128), 256, 0, stream>>>(
                thetaH, phiH, cnt, list, S, b, r0);
            select_kernel<<<dim3(QR), 256, 0, stream>>>(S, cnt, b, r0);
            pv_kernel<<<dim3(QR / 64, 16), 256, 0, stream>>>(
                S, gWT, cnt, gc_part, b, r0);
            scatter_kernel<<<dim3(QR / 2), 256, 0, stream>>>(
                gc_part, cnt, list, gc, b, r0);
        }
    }

    y_kernel<<<dim3(N_ / 64, C_ / 64, B_), 256, 0, stream>>>(gc, Wout, bout, y);
    bn_stats_kernel<<<dim3(C_), 256, 0, stream>>>(y, mean, rsig);
    final_kernel<<<dim3(B_ * C_ * N_ / 256), 256, 0, stream>>>(
        x, y, mean, rsig, gamma, beta, out);
}

// Round 10
// 262.598 us; speedup vs baseline: 1.5054x; 1.2815x over previous
//
#include <hip/hip_runtime.h>

#define B_ 2
#define C_ 256
#define IC_ 128
#define N_ 4096
#define KSEL 2048
#define QR 1024
#define KS_PV 8

// workspace offsets (floats) — total 40.2 MB (ws >= 42.1 MB proven in R3)
#define OFF_GC    0u
#define OFF_Y     1048576u
#define OFF_WEFF  3145728u
#define OFF_BEFF  3178496u
#define OFF_MEAN  3178624u
#define OFF_RSIG  3178880u
#define OFF_CNT   3179136u
#define OFF_LIST  3179200u
#define OFF_THB   3187456u   // theta f16 [B][N][IC]
#define OFF_PHB   3711744u   // phi   f16 [B][N][IC]
#define OFF_GWT   4236032u   // gW^T  f16 [B][IC][N]
#define OFF_XTH   4760320u   // x^T   f16 [B][N][C]
#define OFF_WALL  5808896u   // {Wth,Weff,Wph} f16 [384][256]
#define OFF_BALL  5858048u   // {bth,beff,bph} f32 [384]
#define OFF_S     5858432u   // S/P f16 [B][QR][N] (16 MB)

typedef __attribute__((ext_vector_type(8))) _Float16 f16x8;
typedef __attribute__((ext_vector_type(4))) float f32x4;

__device__ __forceinline__ unsigned short f2h(float f) {
    union { _Float16 h; unsigned short u; } cv;
    cv.h = (_Float16)f;
    return cv.u;
}
__device__ __forceinline__ float h2f(unsigned short u) {
    union { unsigned short u; _Float16 h; } cv;
    cv.u = u;
    return (float)cv.h;
}

// ---------------------------------------------------------------------------
// Weff[o][c] = sum_i Wgcn[i][o] * Wg[i][c];  beff[o] = sum_i Wgcn[i][o]*bg[i]
// ---------------------------------------------------------------------------
__global__ __launch_bounds__(256) void weff_kernel(
    const float* __restrict__ Wg, const float* __restrict__ bg,
    const float* __restrict__ Wgcn, float* __restrict__ Weff,
    float* __restrict__ beff)
{
    const int o = blockIdx.x, c = threadIdx.x;
    float acc = 0.f;
    for (int i = 0; i < IC_; ++i)
        acc = fmaf(Wgcn[i * IC_ + o], Wg[i * C_ + c], acc);
    Weff[o * C_ + c] = acc;
    if (c == 0) {
        float bacc = 0.f;
        for (int i = 0; i < IC_; ++i)
            bacc = fmaf(Wgcn[i * IC_ + o], bg[i], bacc);
        beff[o] = bacc;
    }
}

// ---------------------------------------------------------------------------
// pack {Wth, Weff, Wph} -> WallH f16 [384][256], {bth,beff,bph} -> ball
// ---------------------------------------------------------------------------
__global__ __launch_bounds__(256) void wconv_kernel(
    const float* __restrict__ Wth, const float* __restrict__ bth,
    const float* __restrict__ Weff, const float* __restrict__ beff,
    const float* __restrict__ Wph, const float* __restrict__ bph,
    unsigned short* __restrict__ WallH, float* __restrict__ ball)
{
    const int o = blockIdx.x;          // 0..383
    const int c = threadIdx.x;         // 0..255
    const float* W  = (o < 128) ? Wth : (o < 256) ? Weff : Wph;
    const float* bb = (o < 128) ? bth : (o < 256) ? beff : bph;
    const int oo = o & 127;
    WallH[o * C_ + c] = f2h(W[oo * C_ + c]);
    if (c == 0) ball[o] = bb[oo];
}

// ---------------------------------------------------------------------------
// xT: x [b][c][n] f32 -> xTH [b][n][c] f16.  64x64 LDS transpose tiles.
// grid (N/64, C/64, B)
// ---------------------------------------------------------------------------
__global__ __launch_bounds__(256) void xt_kernel(
    const float* __restrict__ x, unsigned short* __restrict__ xTH)
{
    __shared__ float Xs[64][65];
    const int n0 = blockIdx.x * 64, c0 = blockIdx.y * 64, b = blockIdx.z;
    const int t = threadIdx.x;
#pragma unroll
    for (int s = 0; s < 4; ++s) {
        int e4 = t + 256 * s;            // 1024 float4 = 64c x 16(n/4)
        int cc = e4 >> 4, c4 = e4 & 15;
        float4 v = *(const float4*)&x[((size_t)b * C_ + c0 + cc) * N_ + n0 + c4 * 4];
        Xs[cc][c4 * 4 + 0] = v.x; Xs[cc][c4 * 4 + 1] = v.y;
        Xs[cc][c4 * 4 + 2] = v.z; Xs[cc][c4 * 4 + 3] = v.w;
    }
    __syncthreads();
#pragma unroll
    for (int s = 0; s < 4; ++s) {
        int e = t + 256 * s;             // 1024 ushort4 = 64n x 16(c/4)
        int nn = e >> 4, c4 = e & 15;    // FIX (R9 bug): was >>3 / &7
        ushort4 h;
        h.x = f2h(Xs[c4 * 4 + 0][nn]);
        h.y = f2h(Xs[c4 * 4 + 1][nn]);
        h.z = f2h(Xs[c4 * 4 + 2][nn]);
        h.w = f2h(Xs[c4 * 4 + 3][nn]);
        *(ushort4*)&xTH[((size_t)b * N_ + n0 + nn) * C_ + c0 + c4 * 4] = h;
    }
}

// ---------------------------------------------------------------------------
// proj (MFMA f16): out[o][n] = WallH[pj-chunk] . xT, K=256.
// 128o x 128n tile, 4 waves. pj 0->thetaH[n][o], 1->gWTH[o][n], 2->phiH[n][o]
// grid (N/128, 3, B)
// ---------------------------------------------------------------------------
__global__ __launch_bounds__(256) void proj_kernel(
    const unsigned short* __restrict__ xTH,
    const unsigned short* __restrict__ WallH, const float* __restrict__ ball,
    unsigned short* __restrict__ thetaH, unsigned short* __restrict__ gWTH,
    unsigned short* __restrict__ phiH)
{
    __shared__ unsigned short Xt[128][72];
    __shared__ unsigned short Wt[128][72];
    const int n0 = blockIdx.x * 128;
    const int pj = blockIdx.y;
    const int b  = blockIdx.z;
    const int t = threadIdx.x, w = t >> 6, lane = t & 63;
    const int lrow = lane & 15, lk = (lane >> 4) * 8;
    const int wA = (w >> 1) * 64, wB = (w & 1) * 64;

    f32x4 acc[4][4];
#pragma unroll
    for (int u = 0; u < 4; ++u)
#pragma unroll
        for (int v = 0; v < 4; ++v) acc[u][v] = (f32x4)(0.f);

    for (int kc = 0; kc < C_; kc += 64) {
        __syncthreads();
#pragma unroll
        for (int s = 0; s < 4; ++s) {
            int e4 = t + 256 * s;        // 1024 x 16B
            int r = e4 >> 3, k8 = e4 & 7;
            *(float4*)&Xt[r][k8 * 8] =
                *(const float4*)&xTH[((size_t)b * N_ + n0 + r) * C_ + kc + k8 * 8];
        }
#pragma unroll
        for (int s = 0; s < 4; ++s) {
            int e4 = t + 256 * s;
            int r = e4 >> 3, k8 = e4 & 7;
            *(float4*)&Wt[r][k8 * 8] =
                *(const float4*)&WallH[(size_t)(pj * 128 + r) * C_ + kc + k8 * 8];
        }
        __syncthreads();

#pragma unroll
        for (int kstep = 0; kstep < 2; ++kstep) {
            const int kk = kstep * 32 + lk;
            f16x8 af[4], bf[4];
            if (pj != 1) {               // A = W (o), B = xT (n)
#pragma unroll
                for (int u = 0; u < 4; ++u)
                    af[u] = *(const f16x8*)&Wt[wA + u * 16 + lrow][kk];
#pragma unroll
                for (int v = 0; v < 4; ++v)
                    bf[v] = *(const f16x8*)&Xt[wB + v * 16 + lrow][kk];
            } else {                     // A = xT (n), B = W (o)
#pragma unroll
                for (int u = 0; u < 4; ++u)
                    af[u] = *(const f16x8*)&Xt[wA + u * 16 + lrow][kk];
#pragma unroll
                for (int v = 0; v < 4; ++v)
                    bf[v] = *(const f16x8*)&Wt[wB + v * 16 + lrow][kk];
            }
#pragma unroll
            for (int u = 0; u < 4; ++u)
#pragma unroll
                for (int v = 0; v < 4; ++v)
                    acc[u][v] = __builtin_amdgcn_mfma_f32_16x16x32_f16(
                        af[u], bf[v], acc[u][v], 0, 0, 0);
        }
    }

    const int crow = (lane >> 4) * 4;
    if (pj != 1) {
        unsigned short* dst = (pj == 0) ? thetaH : phiH;
        const int bb2 = (pj == 0) ? 0 : 256;
#pragma unroll
        for (int u = 0; u < 4; ++u) {
            const int ob = wA + u * 16 + crow;
            float b0 = ball[bb2 + ob + 0], b1 = ball[bb2 + ob + 1];
            float b2 = ball[bb2 + ob + 2], b3 = ball[bb2 + ob + 3];
#pragma unroll
            for (int v = 0; v < 4; ++v) {
                const int n = n0 + wB + v * 16 + lrow;
                ushort4 h;
                h.x = f2h(acc[u][v][0] + b0);
                h.y = f2h(acc[u][v][1] + b1);
                h.z = f2h(acc[u][v][2] + b2);
                h.w = f2h(acc[u][v][3] + b3);
                *(ushort4*)&dst[((size_t)b * N_ + n) * IC_ + ob] = h;
            }
        }
    } else {
#pragma unroll
        for (int v = 0; v < 4; ++v) {
            const int o = wB + v * 16 + lrow;
            const float bo = ball[128 + o];
#pragma unroll
            for (int u = 0; u < 4; ++u) {
                const int nb = n0 + wA + u * 16 + crow;
                ushort4 h;
                h.x = f2h(acc[u][v][0] + bo);
                h.y = f2h(acc[u][v][1] + bo);
                h.z = f2h(acc[u][v][2] + bo);
                h.w = f2h(acc[u][v][3] + bo);
                *(ushort4*)&gWTH[((size_t)b * IC_ + o) * N_ + nb] = h;
            }
        }
    }
}

// ---------------------------------------------------------------------------
// hard-row compaction
// ---------------------------------------------------------------------------
__global__ __launch_bounds__(256) void compact_kernel(
    const float* __restrict__ hard_map, int* __restrict__ cnt,
    int* __restrict__ list)
{
    int idx = blockIdx.x * 256 + threadIdx.x;
    if (idx >= B_ * N_) return;
    int b = idx >> 12;
    int n = idx & (N_ - 1);
    if (hard_map[idx] > 0.5f) {
        int p = atomicAdd(&cnt[b], 1);
        list[b * N_ + p] = n;
    }
}

// ---------------------------------------------------------------------------
// score (MFMA f16): SH[b][lr][m] = theta_row(lr) . phi[:,m], f16 out.
// A = phi-rows (m), B = theta-rows (r) -> packed ushort4 stores along m.
// grid (N/128, QR/128, B)
// ---------------------------------------------------------------------------
__global__ __launch_bounds__(256) void score_kernel(
    const unsigned short* __restrict__ thetaH,
    const unsigned short* __restrict__ phiH,
    const int* __restrict__ cnt, const int* __restrict__ list,
    unsigned short* __restrict__ SH, int r0base)
{
    __shared__ unsigned short Th[128][136];
    __shared__ unsigned short Ph[128][136];
    __shared__ int sIdx[128];

    const int b = blockIdx.z;
    const int count = cnt[b];
    const int lr0 = blockIdx.y * 128;
    if (r0base + lr0 >= count) return;
    const int m0 = blockIdx.x * 128;
    const int t = threadIdx.x;
    const int w = t >> 6, lane = t & 63;

    if (t < 128) {
        int gr = r0base + lr0 + t;
        sIdx[t] = (gr < count) ? list[b * N_ + gr] : -1;
    }
    __syncthreads();

#pragma unroll
    for (int s = 0; s < 8; ++s) {
        int e4 = t + 256 * s;
        int r = e4 >> 4, k4 = e4 & 15;
        int gr = sIdx[r];
        float4 v = make_float4(0.f, 0.f, 0.f, 0.f);
        if (gr >= 0)
            v = *(const float4*)&thetaH[((size_t)b * N_ + gr) * IC_ + k4 * 8];
        *(float4*)&Th[r][k4 * 8] = v;
    }
#pragma unroll
    for (int s = 0; s < 8; ++s) {
        int e4 = t + 256 * s;
        int r = e4 >> 4, k4 = e4 & 15;
        *(float4*)&Ph[r][k4 * 8] =
            *(const float4*)&phiH[((size_t)b * N_ + m0 + r) * IC_ + k4 * 8];
    }
    __syncthreads();

    const int wm = (w >> 1) * 64, wr = (w & 1) * 64;
    const int lrow = lane & 15, lk = (lane >> 4) * 8;

    f32x4 acc[4][4];
#pragma unroll
    for (int u = 0; u < 4; ++u)
#pragma unroll
        for (int v = 0; v < 4; ++v) acc[u][v] = (f32x4)(0.f);

#pragma unroll
    for (int ks = 0; ks < 4; ++ks) {
        const int kk = ks * 32 + lk;
        f16x8 af[4], bf[4];
#pragma unroll
        for (int u = 0; u < 4; ++u)
            af[u] = *(const f16x8*)&Ph[wm + u * 16 + lrow][kk];
#pragma unroll
        for (int v = 0; v < 4; ++v)
            bf[v] = *(const f16x8*)&Th[wr + v * 16 + lrow][kk];
#pragma unroll
        for (int u = 0; u < 4; ++u)
#pragma unroll
            for (int v = 0; v < 4; ++v)
                acc[u][v] = __builtin_amdgcn_mfma_f32_16x16x32_f16(
                    af[u], bf[v], acc[u][v], 0, 0, 0);
    }

    const int crow = (lane >> 4) * 4;
#pragma unroll
    for (int u = 0; u < 4; ++u) {
        const int mb = m0 + wm + u * 16 + crow;
#pragma unroll
        for (int v = 0; v < 4; ++v) {
            const int r = lr0 + wr + v * 16 + lrow;
            ushort4 h;
            h.x = f2h(acc[u][v][0]);
            h.y = f2h(acc[u][v][1]);
            h.z = f2h(acc[u][v][2]);
            h.w = f2h(acc[u][v][3]);
            *(ushort4*)&SH[((size_t)b * QR + r) * N_ + mb] = h;
        }
    }
}

// ---------------------------------------------------------------------------
// select: exact kth-largest radix select (2x8-bit passes on monotone u16)
// + softmax; writes P f16 in place. grid (QR, B)
// ---------------------------------------------------------------------------
__global__ __launch_bounds__(256) void select_kernel(
    unsigned short* __restrict__ SH, const int* __restrict__ cnt, int r0base)
{
    __shared__ unsigned int sHist[4][256];
    __shared__ unsigned int sWsum[4];
    __shared__ float sRed[8];
    __shared__ unsigned int sPrefix, sRemain;

    const int b = blockIdx.y;
    const int lr = blockIdx.x;
    if (r0base + lr >= cnt[b]) return;
    const int t = threadIdx.x, lane = t & 63, wid = t >> 6;

    uint4* row = (uint4*)(SH + ((size_t)b * QR + lr) * N_);
    uint4 rv[2];
    rv[0] = row[t];
    rv[1] = row[t + 256];

    float sv[16];
    unsigned int mu[16];
#pragma unroll
    for (int q = 0; q < 2; ++q) {
        const unsigned int* pu = (const unsigned int*)&rv[q];
#pragma unroll
        for (int dw = 0; dw < 4; ++dw) {
            unsigned int u = pu[dw];
            unsigned short h0 = (unsigned short)(u & 0xffffu);
            unsigned short h1 = (unsigned short)(u >> 16);
            int e = q * 8 + dw * 2;
            sv[e]     = h2f(h0);
            sv[e + 1] = h2f(h1);
            mu[e]     = (h0 & 0x8000u) ? (unsigned int)((~h0) & 0xffffu)
                                       : (unsigned int)(h0 | 0x8000u);
            mu[e + 1] = (h1 & 0x8000u) ? (unsigned int)((~h1) & 0xffffu)
                                       : (unsigned int)(h1 | 0x8000u);
        }
    }

    float m = -3.4e38f;
#pragma unroll
    for (int e = 0; e < 16; ++e) m = fmaxf(m, sv[e]);
#pragma unroll
    for (int off = 32; off > 0; off >>= 1) m = fmaxf(m, __shfl_xor(m, off));
    if (lane == 0) sRed[wid] = m;
    __syncthreads();
    m = fmaxf(fmaxf(sRed[0], sRed[1]), fmaxf(sRed[2], sRed[3]));

    unsigned int prefix = 0u;
    unsigned int remain = KSEL;
    for (int d = 1; d >= 0; --d) {
        __syncthreads();
#pragma unroll
        for (int ww = 0; ww < 4; ++ww) sHist[ww][t] = 0u;
        __syncthreads();
#pragma unroll
        for (int e = 0; e < 16; ++e) {
            if ((mu[e] >> (8 * (d + 1))) == prefix)
                atomicAdd(&sHist[wid][(mu[e] >> (8 * d)) & 255u], 1u);
        }
        __syncthreads();
        unsigned int x = sHist[0][t] + sHist[1][t] + sHist[2][t] + sHist[3][t];
        unsigned int own = x;
#pragma unroll
        for (int off = 1; off < 64; off <<= 1) {
            unsigned int y = __shfl_down(x, off);
            if (lane + off < 64) x += y;
        }
        if (lane == 0) sWsum[wid] = x;
        __syncthreads();
        for (int ww = wid + 1; ww < 4; ++ww) x += sWsum[ww];
        unsigned int nxt = x - own;
        if (x >= remain && nxt < remain) {
            sPrefix = (prefix << 8) | (unsigned int)t;
            sRemain = remain - nxt;
        }
        __syncthreads();
        prefix = sPrefix;
        remain = sRemain;
    }
    const unsigned int tu = prefix;

    float z = 0.f, ssel = 0.f;
#pragma unroll
    for (int e = 0; e < 16; ++e) {
        float ex = expf(sv[e] - m);
        z += ex;
        if (mu[e] >= tu) ssel += ex;
    }
#pragma unroll
    for (int off = 32; off > 0; off >>= 1) {
        z    += __shfl_xor(z, off);
        ssel += __shfl_xor(ssel, off);
    }
    __syncthreads();
    if (lane == 0) { sRed[wid] = z; sRed[4 + wid] = ssel; }
    __syncthreads();
    const float zt = sRed[0] + sRed[1] + sRed[2] + sRed[3];
    const float st = sRed[4] + sRed[5] + sRed[6] + sRed[7];
    const float inv = 1.f / (st + 1e-6f * zt);

#pragma unroll
    for (int q = 0; q < 2; ++q) {
        unsigned int* pu = (unsigned int*)&rv[q];
#pragma unroll
        for (int dw = 0; dw < 4; ++dw) {
            int e = q * 8 + dw * 2;
            unsigned int p0 = (mu[e] >= tu) ? (unsigned int)f2h(expf(sv[e] - m) * inv) : 0u;
            unsigned int p1 = (mu[e + 1] >= tu) ? (unsigned int)f2h(expf(sv[e + 1] - m) * inv) : 0u;
            pu[dw] = p0 | (p1 << 16);
        }
    }
    row[t]       = rv[0];
    row[t + 256] = rv[1];
}

// ---------------------------------------------------------------------------
// pv (MFMA f16, split-K=8): gc_part[b][ks][lr][i] over j in ks*512..+512.
// A = gWT-rows (i), B = P-rows (r) -> float4 stores along i.
// grid (QR/64, 8, B)
// ---------------------------------------------------------------------------
__global__ __launch_bounds__(256) void pv_kernel(
    const unsigned short* __restrict__ SH, const unsigned short* __restrict__ gWTH,
    const int* __restrict__ cnt, float* __restrict__ gc_part, int r0base)
{
    __shared__ unsigned short Pt[64][72];
    __shared__ unsigned short Gt[128][72];

    const int b = blockIdx.z;
    const int count = cnt[b];
    const int lr0 = blockIdx.x * 64;
    if (r0base + lr0 >= count) return;
    const int ks = blockIdx.y;
    const int t = threadIdx.x;
    const int w = t >> 6, lane = t & 63;
    const int lrow = lane & 15, lk = (lane >> 4) * 8;
    const int wiA = (w & 1) * 64, wrB = (w >> 1) * 32;

    f32x4 acc[4][2];
#pragma unroll
    for (int u = 0; u < 4; ++u)
#pragma unroll
        for (int v = 0; v < 2; ++v) acc[u][v] = (f32x4)(0.f);

    for (int jc = ks * 512; jc < ks * 512 + 512; jc += 64) {
        __syncthreads();
#pragma unroll
        for (int s = 0; s < 2; ++s) {
            int e4 = t + 256 * s;             // 512 x 16B
            int r = e4 >> 3, k8 = e4 & 7;
            *(float4*)&Pt[r][k8 * 8] =
                *(const float4*)&SH[((size_t)b * QR + lr0 + r) * N_ + jc + k8 * 8];
        }
#pragma unroll
        for (int s = 0; s < 4; ++s) {
            int e4 = t + 256 * s;             // 1024 x 16B
            int i = e4 >> 3, k8 = e4 & 7;
            *(float4*)&Gt[i][k8 * 8] =
                *(const float4*)&gWTH[((size_t)b * IC_ + i) * N_ + jc + k8 * 8];
        }
        __syncthreads();

#pragma unroll
        for (int kstep = 0; kstep < 2; ++kstep) {
            const int kk = kstep * 32 + lk;
            f16x8 af[4], bf[2];
#pragma unroll
            for (int u = 0; u < 4; ++u)
                af[u] = *(const f16x8*)&Gt[wiA + u * 16 + lrow][kk];
#pragma unroll
            for (int v = 0; v < 2; ++v)
                bf[v] = *(const f16x8*)&Pt[wrB + v * 16 + lrow][kk];
#pragma unroll
            for (int u = 0; u < 4; ++u)
#pragma unroll
                for (int v = 0; v < 2; ++v)
                    acc[u][v] = __builtin_amdgcn_mfma_f32_16x16x32_f16(
                        af[u], bf[v], acc[u][v], 0, 0, 0);
        }
    }

    const int crow = (lane >> 4) * 4;
#pragma unroll
    for (int u = 0; u < 4; ++u) {
        const int ib = wiA + u * 16 + crow;
#pragma unroll
        for (int v = 0; v < 2; ++v) {
            const int r = lr0 + wrB + v * 16 + lrow;
            *(float4*)&gc_part[(((size_t)b * KS_PV + ks) * QR + r) * IC_ + ib] =
                make_float4(acc[u][v][0], acc[u][v][1], acc[u][v][2], acc[u][v][3]);
        }
    }
}

// ---------------------------------------------------------------------------
// reduce split-K partials, ReLU, scatter to gc[b][n][i]. grid (QR*IC/256, B)
// ---------------------------------------------------------------------------
__global__ __launch_bounds__(256) void scatter_kernel(
    const float* __restrict__ gc_part, const int* __restrict__ cnt,
    const int* __restrict__ list, float* __restrict__ gc, int r0base)
{
    const int b = blockIdx.y;
    int idx = blockIdx.x * 256 + threadIdx.x;
    int lr = idx >> 7, i = idx & 127;
    if (r0base + lr >= cnt[b]) return;
    float v = 0.f;
#pragma unroll
    for (int ks = 0; ks < KS_PV; ++ks)
        v += gc_part[(((size_t)b * KS_PV + ks) * QR + lr) * IC_ + i];
    int n = list[b * N_ + r0base + lr];
    gc[((size_t)b * N_ + n) * IC_ + i] = fmaxf(v, 0.f);
}

// ---------------------------------------------------------------------------
// y[b,c,n] = Wout[c,:] . gc[b,n,:] + bout[c].  64c x 64n tiles.
// ---------------------------------------------------------------------------
__global__ __launch_bounds__(256) void y_kernel(
    const float* __restrict__ gc, const float* __restrict__ Wout,
    const float* __restrict__ bout, float* __restrict__ y)
{
    __shared__ float Wt[64][33];
    __shared__ float Gt[32][68];
    const int n0 = blockIdx.x * 64;
    const int c0 = blockIdx.y * 64;
    const int b  = blockIdx.z;
    const int t = threadIdx.x;
    const int tx = t & 15, ty = t >> 4;

    float acc[4][4];
#pragma unroll
    for (int u = 0; u < 4; ++u)
#pragma unroll
        for (int v = 0; v < 4; ++v) acc[u][v] = 0.f;

    for (int kc = 0; kc < IC_; kc += 32) {
        __syncthreads();
#pragma unroll
        for (int s = 0; s < 2; ++s) {
            int e4 = t + 256 * s;
            int c = e4 >> 3, k4 = e4 & 7;
            float4 ww = *(const float4*)&Wout[(size_t)(c0 + c) * IC_ + kc + k4 * 4];
            Wt[c][k4 * 4 + 0] = ww.x; Wt[c][k4 * 4 + 1] = ww.y;
            Wt[c][k4 * 4 + 2] = ww.z; Wt[c][k4 * 4 + 3] = ww.w;
        }
#pragma unroll
        for (int s = 0; s < 2; ++s) {
            int e4 = t + 256 * s;
            int nn = e4 >> 3, k4 = e4 & 7;
            float4 g = *(const float4*)&gc[((size_t)b * N_ + n0 + nn) * IC_ + kc + k4 * 4];
            Gt[k4 * 4 + 0][nn] = g.x; Gt[k4 * 4 + 1][nn] = g.y;
            Gt[k4 * 4 + 2][nn] = g.z; Gt[k4 * 4 + 3][nn] = g.w;
        }
        __syncthreads();

#pragma unroll 4
        for (int k = 0; k < 32; ++k) {
            float a[4];
#pragma unroll
            for (int u = 0; u < 4; ++u) a[u] = Wt[ty * 4 + u][k];
            const float4 g4 = *(const float4*)&Gt[k][tx * 4];
            const float gm[4] = {g4.x, g4.y, g4.z, g4.w};
#pragma unroll
            for (int u = 0; u < 4; ++u)
#pragma unroll
                for (int v = 0; v < 4; ++v)
                    acc[u][v] = fmaf(a[u], gm[v], acc[u][v]);
        }
    }

#pragma unroll
    for (int u = 0; u < 4; ++u) {
        const int c = c0 + ty * 4 + u;
        const float bo = bout[c];
        *(float4*)&y[((size_t)b * C_ + c) * N_ + n0 + tx * 4] =
            make_float4(acc[u][0] + bo, acc[u][1] + bo,
                        acc[u][2] + bo, acc[u][3] + bo);
    }
}

// ---------------------------------------------------------------------------
// BatchNorm stats per channel
// ---------------------------------------------------------------------------
__global__ __launch_bounds__(256) void bn_stats_kernel(
    const float* __restrict__ y, float* __restrict__ mean,
    float* __restrict__ rsig)
{
    __shared__ float sr[8];
    const int c = blockIdx.x, t = threadIdx.x;
    const int lane = t & 63, wid = t >> 6;
    float s = 0.f, ss = 0.f;
    for (int b = 0; b < B_; ++b) {
        const float* yr = y + ((size_t)b * C_ + c) * N_;
        for (int n = t; n < N_; n += 256) {
            float v = yr[n];
            s += v; ss = fmaf(v, v, ss);
        }
    }
#pragma unroll
    for (int off = 32; off > 0; off >>= 1) {
        s  += __shfl_xor(s, off);
        ss += __shfl_xor(ss, off);
    }
    if (lane == 0) { sr[wid] = s; sr[4 + wid] = ss; }
    __syncthreads();
    if (t == 0) {
        float st  = sr[0] + sr[1] + sr[2] + sr[3];
        float sst = sr[4] + sr[5] + sr[6] + sr[7];
        float mu  = st / (float)(B_ * N_);
        float var = sst / (float)(B_ * N_) - mu * mu;
        mean[c] = mu;
        rsig[c] = rsqrtf(var + 1e-5f);
    }
}

// ---------------------------------------------------------------------------
// out = x + gamma*(y-mean)*rsig + beta
// ---------------------------------------------------------------------------
__global__ __launch_bounds__(256) void final_kernel(
    const float* __restrict__ x, const float* __restrict__ y,
    const float* __restrict__ mean, const float* __restrict__ rsig,
    const float* __restrict__ gamma, const float* __restrict__ beta,
    float* __restrict__ out)
{
    int idx = blockIdx.x * 256 + threadIdx.x;
    if (idx >= B_ * C_ * N_) return;
    int c = (idx >> 12) & (C_ - 1);
    out[idx] = x[idx] + fmaf(gamma[c], (y[idx] - mean[c]) * rsig[c], beta[c]);
}

extern "C" void kernel_launch(void* const* d_in, const int* in_sizes, int n_in,
                              void* d_out, int out_size, void* d_ws, size_t ws_size,
                              hipStream_t stream)
{
    const float* x     = (const float*)d_in[0];
    const float* hard  = (const float*)d_in[1];
    const float* Wg    = (const float*)d_in[2];
    const float* bg    = (const float*)d_in[3];
    const float* Wth   = (const float*)d_in[4];
    const float* bth   = (const float*)d_in[5];
    const float* Wph   = (const float*)d_in[6];
    const float* bph   = (const float*)d_in[7];
    const float* Wgcn  = (const float*)d_in[8];
    const float* Wout  = (const float*)d_in[9];
    const float* bout  = (const float*)d_in[10];
    const float* gamma = (const float*)d_in[11];
    const float* beta  = (const float*)d_in[12];
    float* out = (float*)d_out;
    float* ws  = (float*)d_ws;

    float* gc    = ws + OFF_GC;
    float* y     = ws + OFF_Y;
    float* Weff  = ws + OFF_WEFF;
    float* beff  = ws + OFF_BEFF;
    float* mean  = ws + OFF_MEAN;
    float* rsig  = ws + OFF_RSIG;
    int*   cnt   = (int*)(ws + OFF_CNT);
    int*   list  = (int*)(ws + OFF_LIST);
    unsigned short* thetaH = (unsigned short*)(ws + OFF_THB);
    unsigned short* phiH   = (unsigned short*)(ws + OFF_PHB);
    unsigned short* gWTH   = (unsigned short*)(ws + OFF_GWT);
    unsigned short* xTH    = (unsigned short*)(ws + OFF_XTH);
    unsigned short* WallH  = (unsigned short*)(ws + OFF_WALL);
    float* ball  = ws + OFF_BALL;
    unsigned short* SH = (unsigned short*)(ws + OFF_S);
    float* gc_part = out;   // d_out (8 MB = B*KS_PV*QR*IC*4) as split-K
                            // scratch; fully overwritten by final_kernel.

    hipMemsetAsync(cnt, 0, 2 * sizeof(int), stream);
    hipMemsetAsync(gc, 0, (size_t)B_ * N_ * IC_ * sizeof(float), stream);

    weff_kernel<<<dim3(IC_), 256, 0, stream>>>(Wg, bg, Wgcn, Weff, beff);
    wconv_kernel<<<dim3(384), 256, 0, stream>>>(
        Wth, bth, Weff, beff, Wph, bph, WallH, ball);
    xt_kernel<<<dim3(N_ / 64, C_ / 64, B_), 256, 0, stream>>>(x, xTH);
    proj_kernel<<<dim3(N_ / 128, 3, B_), 256, 0, stream>>>(
        xTH, WallH, ball, thetaH, gWTH, phiH);
    compact_kernel<<<dim3(B_ * N_ / 256), 256, 0, stream>>>(hard, cnt, list);

    for (int r0 = 0; r0 < N_; r0 += QR) {
        score_kernel<<<dim3(N_ / 128, QR / 128, B_), 256, 0, stream>>>(
            thetaH, phiH, cnt, list, SH, r0);
        select_kernel<<<dim3(QR, B_), 256, 0, stream>>>(SH, cnt, r0);
        pv_kernel<<<dim3(QR / 64, KS_PV, B_), 256, 0, stream>>>(
            SH, gWTH, cnt, gc_part, r0);
        scatter_kernel<<<dim3(QR * IC_ / 256, B_), 256, 0, stream>>>(
            gc_part, cnt, list, gc, r0);
    }

    y_kernel<<<dim3(N_ / 64, C_ / 64, B_), 256, 0, stream>>>(gc, Wout, bout, y);
    bn_stats_kernel<<<dim3(C_), 256, 0, stream>>>(y, mean, rsig);
    final_kernel<<<dim3(B_ * C_ * N_ / 256), 256, 0, stream>>>(
        x, y, mean, rsig, gamma, beta, out);
}

// Round 11
// 213.205 us; speedup vs baseline: 1.8542x; 1.2317x over previous
//
#include <hip/hip_runtime.h>

#define B_ 2
#define C_ 256
#define IC_ 128
#define N_ 4096
#define KSEL 2048
#define QR 1024
#define KS_PV 8

// workspace offsets (floats) — total 40.2 MB (ws >= 42.1 MB proven in R3)
#define OFF_GC    0u
#define OFF_Y     1048576u
#define OFF_WEFF  3145728u
#define OFF_BEFF  3178496u
#define OFF_MEAN  3178624u
#define OFF_RSIG  3178880u
#define OFF_CNT   3179136u
#define OFF_LIST  3179200u
#define OFF_THB   3187456u   // theta f16 [B][N][IC]
#define OFF_PHB   3711744u   // phi   f16 [B][N][IC]
#define OFF_GWT   4236032u   // gW^T  f16 [B][IC][N]
#define OFF_XTH   4760320u   // x^T   f16 [B][N][C]
#define OFF_WALL  5808896u   // {Wth,Weff,Wph} f16 [384][256]
#define OFF_BALL  5858048u   // {bth,beff,bph} f32 [384]
#define OFF_S     5858432u   // S/P f16 [B][QR][N] (16 MB)

typedef __attribute__((ext_vector_type(8))) _Float16 f16x8;
typedef __attribute__((ext_vector_type(4))) float f32x4;

__device__ __forceinline__ unsigned short f2h(float f) {
    union { _Float16 h; unsigned short u; } cv;
    cv.h = (_Float16)f;
    return cv.u;
}
__device__ __forceinline__ float h2f(unsigned short u) {
    union { unsigned short u; _Float16 h; } cv;
    cv.u = u;
    return (float)cv.h;
}

// ---------------------------------------------------------------------------
// Weff[o][c] = sum_i Wgcn[i][o] * Wg[i][c];  beff[o] = sum_i Wgcn[i][o]*bg[i]
// ---------------------------------------------------------------------------
__global__ __launch_bounds__(256) void weff_kernel(
    const float* __restrict__ Wg, const float* __restrict__ bg,
    const float* __restrict__ Wgcn, float* __restrict__ Weff,
    float* __restrict__ beff)
{
    const int o = blockIdx.x, c = threadIdx.x;
    float acc = 0.f;
    for (int i = 0; i < IC_; ++i)
        acc = fmaf(Wgcn[i * IC_ + o], Wg[i * C_ + c], acc);
    Weff[o * C_ + c] = acc;
    if (c == 0) {
        float bacc = 0.f;
        for (int i = 0; i < IC_; ++i)
            bacc = fmaf(Wgcn[i * IC_ + o], bg[i], bacc);
        beff[o] = bacc;
    }
}

// ---------------------------------------------------------------------------
// pack {Wth, Weff, Wph} -> WallH f16 [384][256], {bth,beff,bph} -> ball
// ---------------------------------------------------------------------------
__global__ __launch_bounds__(256) void wconv_kernel(
    const float* __restrict__ Wth, const float* __restrict__ bth,
    const float* __restrict__ Weff, const float* __restrict__ beff,
    const float* __restrict__ Wph, const float* __restrict__ bph,
    unsigned short* __restrict__ WallH, float* __restrict__ ball)
{
    const int o = blockIdx.x;          // 0..383
    const int c = threadIdx.x;         // 0..255
    const float* W  = (o < 128) ? Wth : (o < 256) ? Weff : Wph;
    const float* bb = (o < 128) ? bth : (o < 256) ? beff : bph;
    const int oo = o & 127;
    WallH[o * C_ + c] = f2h(W[oo * C_ + c]);
    if (c == 0) ball[o] = bb[oo];
}

// ---------------------------------------------------------------------------
// xT: x [b][c][n] f32 -> xTH [b][n][c] f16.  64x64 LDS transpose tiles.
// grid (N/64, C/64, B)
// ---------------------------------------------------------------------------
__global__ __launch_bounds__(256) void xt_kernel(
    const float* __restrict__ x, unsigned short* __restrict__ xTH)
{
    __shared__ float Xs[64][65];
    const int n0 = blockIdx.x * 64, c0 = blockIdx.y * 64, b = blockIdx.z;
    const int t = threadIdx.x;
#pragma unroll
    for (int s = 0; s < 4; ++s) {
        int e4 = t + 256 * s;            // 1024 float4 = 64c x 16(n/4)
        int cc = e4 >> 4, c4 = e4 & 15;
        float4 v = *(const float4*)&x[((size_t)b * C_ + c0 + cc) * N_ + n0 + c4 * 4];
        Xs[cc][c4 * 4 + 0] = v.x; Xs[cc][c4 * 4 + 1] = v.y;
        Xs[cc][c4 * 4 + 2] = v.z; Xs[cc][c4 * 4 + 3] = v.w;
    }
    __syncthreads();
#pragma unroll
    for (int s = 0; s < 4; ++s) {
        int e = t + 256 * s;             // 1024 ushort4 = 64n x 16(c/4)
        int nn = e >> 4, c4 = e & 15;
        ushort4 h;
        h.x = f2h(Xs[c4 * 4 + 0][nn]);
        h.y = f2h(Xs[c4 * 4 + 1][nn]);
        h.z = f2h(Xs[c4 * 4 + 2][nn]);
        h.w = f2h(Xs[c4 * 4 + 3][nn]);
        *(ushort4*)&xTH[((size_t)b * N_ + n0 + nn) * C_ + c0 + c4 * 4] = h;
    }
}

// ---------------------------------------------------------------------------
// proj (MFMA f16): out[o][n] = WallH[pj-chunk] . xT, K=256.
// 128o x 128n tile, 4 waves. pj 0->thetaH[n][o], 1->gWTH[o][n], 2->phiH[n][o]
// grid (N/128, 3, B)
// ---------------------------------------------------------------------------
__global__ __launch_bounds__(256) void proj_kernel(
    const unsigned short* __restrict__ xTH,
    const unsigned short* __restrict__ WallH, const float* __restrict__ ball,
    unsigned short* __restrict__ thetaH, unsigned short* __restrict__ gWTH,
    unsigned short* __restrict__ phiH)
{
    __shared__ unsigned short Xt[128][72];
    __shared__ unsigned short Wt[128][72];
    const int n0 = blockIdx.x * 128;
    const int pj = blockIdx.y;
    const int b  = blockIdx.z;
    const int t = threadIdx.x, w = t >> 6, lane = t & 63;
    const int lrow = lane & 15, lk = (lane >> 4) * 8;
    const int wA = (w >> 1) * 64, wB = (w & 1) * 64;

    f32x4 acc[4][4];
#pragma unroll
    for (int u = 0; u < 4; ++u)
#pragma unroll
        for (int v = 0; v < 4; ++v) acc[u][v] = (f32x4)(0.f);

    for (int kc = 0; kc < C_; kc += 64) {
        __syncthreads();
#pragma unroll
        for (int s = 0; s < 4; ++s) {
            int e4 = t + 256 * s;        // 1024 x 16B
            int r = e4 >> 3, k8 = e4 & 7;
            *(float4*)&Xt[r][k8 * 8] =
                *(const float4*)&xTH[((size_t)b * N_ + n0 + r) * C_ + kc + k8 * 8];
        }
#pragma unroll
        for (int s = 0; s < 4; ++s) {
            int e4 = t + 256 * s;
            int r = e4 >> 3, k8 = e4 & 7;
            *(float4*)&Wt[r][k8 * 8] =
                *(const float4*)&WallH[(size_t)(pj * 128 + r) * C_ + kc + k8 * 8];
        }
        __syncthreads();

#pragma unroll
        for (int kstep = 0; kstep < 2; ++kstep) {
            const int kk = kstep * 32 + lk;
            f16x8 af[4], bf[4];
            if (pj != 1) {               // A = W (o), B = xT (n)
#pragma unroll
                for (int u = 0; u < 4; ++u)
                    af[u] = *(const f16x8*)&Wt[wA + u * 16 + lrow][kk];
#pragma unroll
                for (int v = 0; v < 4; ++v)
                    bf[v] = *(const f16x8*)&Xt[wB + v * 16 + lrow][kk];
            } else {                     // A = xT (n), B = W (o)
#pragma unroll
                for (int u = 0; u < 4; ++u)
                    af[u] = *(const f16x8*)&Xt[wA + u * 16 + lrow][kk];
#pragma unroll
                for (int v = 0; v < 4; ++v)
                    bf[v] = *(const f16x8*)&Wt[wB + v * 16 + lrow][kk];
            }
#pragma unroll
            for (int u = 0; u < 4; ++u)
#pragma unroll
                for (int v = 0; v < 4; ++v)
                    acc[u][v] = __builtin_amdgcn_mfma_f32_16x16x32_f16(
                        af[u], bf[v], acc[u][v], 0, 0, 0);
        }
    }

    const int crow = (lane >> 4) * 4;
    if (pj != 1) {
        unsigned short* dst = (pj == 0) ? thetaH : phiH;
        const int bb2 = (pj == 0) ? 0 : 256;
#pragma unroll
        for (int u = 0; u < 4; ++u) {
            const int ob = wA + u * 16 + crow;
            float b0 = ball[bb2 + ob + 0], b1 = ball[bb2 + ob + 1];
            float b2 = ball[bb2 + ob + 2], b3 = ball[bb2 + ob + 3];
#pragma unroll
            for (int v = 0; v < 4; ++v) {
                const int n = n0 + wB + v * 16 + lrow;
                ushort4 h;
                h.x = f2h(acc[u][v][0] + b0);
                h.y = f2h(acc[u][v][1] + b1);
                h.z = f2h(acc[u][v][2] + b2);
                h.w = f2h(acc[u][v][3] + b3);
                *(ushort4*)&dst[((size_t)b * N_ + n) * IC_ + ob] = h;
            }
        }
    } else {
#pragma unroll
        for (int v = 0; v < 4; ++v) {
            const int o = wB + v * 16 + lrow;
            const float bo = ball[128 + o];
#pragma unroll
            for (int u = 0; u < 4; ++u) {
                const int nb = n0 + wA + u * 16 + crow;
                ushort4 h;
                h.x = f2h(acc[u][v][0] + bo);
                h.y = f2h(acc[u][v][1] + bo);
                h.z = f2h(acc[u][v][2] + bo);
                h.w = f2h(acc[u][v][3] + bo);
                *(ushort4*)&gWTH[((size_t)b * IC_ + o) * N_ + nb] = h;
            }
        }
    }
}

// ---------------------------------------------------------------------------
// hard-row compaction — atomic-free block scan. One block per batch,
// 1024 threads x 4 elements, ascending-n deterministic order.
// ---------------------------------------------------------------------------
__global__ __launch_bounds__(1024) void compact_kernel(
    const float* __restrict__ hard_map, int* __restrict__ cnt,
    int* __restrict__ list)
{
    __shared__ int wsum[16];
    const int b = blockIdx.x;
    const int t = threadIdx.x, lane = t & 63, wid = t >> 6;
    const float* hm = hard_map + (size_t)b * N_;

    float4 v = *(const float4*)&hm[t * 4];
    int f0 = v.x > 0.5f, f1 = v.y > 0.5f, f2 = v.z > 0.5f, f3 = v.w > 0.5f;
    const int c = f0 + f1 + f2 + f3;

    // inclusive scan within wave
    int x = c;
#pragma unroll
    for (int off = 1; off < 64; off <<= 1) {
        int y = __shfl_up(x, off);
        if (lane >= off) x += y;
    }
    if (lane == 63) wsum[wid] = x;
    __syncthreads();
    int base = 0;
    for (int ww = 0; ww < wid; ++ww) base += wsum[ww];
    int pos = base + x - c;              // exclusive prefix for this thread

    int* lst = list + b * N_;
    int n = t * 4;
    if (f0) lst[pos++] = n;
    if (f1) lst[pos++] = n + 1;
    if (f2) lst[pos++] = n + 2;
    if (f3) lst[pos++] = n + 3;

    if (t == 0) {
        int tot = 0;
#pragma unroll
        for (int ww = 0; ww < 16; ++ww) tot += wsum[ww];
        cnt[b] = tot;
    }
}

// ---------------------------------------------------------------------------
// score (MFMA f16): SH[b][lr][m] = theta_row(lr) . phi[:,m], f16 out.
// A = phi-rows (m), B = theta-rows (r) -> packed ushort4 stores along m.
// grid (N/128, QR/128, B)
// ---------------------------------------------------------------------------
__global__ __launch_bounds__(256) void score_kernel(
    const unsigned short* __restrict__ thetaH,
    const unsigned short* __restrict__ phiH,
    const int* __restrict__ cnt, const int* __restrict__ list,
    unsigned short* __restrict__ SH, int r0base)
{
    __shared__ unsigned short Th[128][136];
    __shared__ unsigned short Ph[128][136];
    __shared__ int sIdx[128];

    const int b = blockIdx.z;
    const int count = cnt[b];
    const int lr0 = blockIdx.y * 128;
    if (r0base + lr0 >= count) return;
    const int m0 = blockIdx.x * 128;
    const int t = threadIdx.x;
    const int w = t >> 6, lane = t & 63;

    if (t < 128) {
        int gr = r0base + lr0 + t;
        sIdx[t] = (gr < count) ? list[b * N_ + gr] : -1;
    }
    __syncthreads();

#pragma unroll
    for (int s = 0; s < 8; ++s) {
        int e4 = t + 256 * s;
        int r = e4 >> 4, k4 = e4 & 15;
        int gr = sIdx[r];
        float4 v = make_float4(0.f, 0.f, 0.f, 0.f);
        if (gr >= 0)
            v = *(const float4*)&thetaH[((size_t)b * N_ + gr) * IC_ + k4 * 8];
        *(float4*)&Th[r][k4 * 8] = v;
    }
#pragma unroll
    for (int s = 0; s < 8; ++s) {
        int e4 = t + 256 * s;
        int r = e4 >> 4, k4 = e4 & 15;
        *(float4*)&Ph[r][k4 * 8] =
            *(const float4*)&phiH[((size_t)b * N_ + m0 + r) * IC_ + k4 * 8];
    }
    __syncthreads();

    const int wm = (w >> 1) * 64, wr = (w & 1) * 64;
    const int lrow = lane & 15, lk = (lane >> 4) * 8;

    f32x4 acc[4][4];
#pragma unroll
    for (int u = 0; u < 4; ++u)
#pragma unroll
        for (int v = 0; v < 4; ++v) acc[u][v] = (f32x4)(0.f);

#pragma unroll
    for (int ks = 0; ks < 4; ++ks) {
        const int kk = ks * 32 + lk;
        f16x8 af[4], bf[4];
#pragma unroll
        for (int u = 0; u < 4; ++u)
            af[u] = *(const f16x8*)&Ph[wm + u * 16 + lrow][kk];
#pragma unroll
        for (int v = 0; v < 4; ++v)
            bf[v] = *(const f16x8*)&Th[wr + v * 16 + lrow][kk];
#pragma unroll
        for (int u = 0; u < 4; ++u)
#pragma unroll
            for (int v = 0; v < 4; ++v)
                acc[u][v] = __builtin_amdgcn_mfma_f32_16x16x32_f16(
                    af[u], bf[v], acc[u][v], 0, 0, 0);
    }

    const int crow = (lane >> 4) * 4;
#pragma unroll
    for (int u = 0; u < 4; ++u) {
        const int mb = m0 + wm + u * 16 + crow;
#pragma unroll
        for (int v = 0; v < 4; ++v) {
            const int r = lr0 + wr + v * 16 + lrow;
            ushort4 h;
            h.x = f2h(acc[u][v][0]);
            h.y = f2h(acc[u][v][1]);
            h.z = f2h(acc[u][v][2]);
            h.w = f2h(acc[u][v][3]);
            *(ushort4*)&SH[((size_t)b * QR + r) * N_ + mb] = h;
        }
    }
}

// ---------------------------------------------------------------------------
// select: exact kth-largest radix select (2x8-bit passes on monotone u16)
// + softmax; writes P f16 in place. grid (QR, B)
// ---------------------------------------------------------------------------
__global__ __launch_bounds__(256) void select_kernel(
    unsigned short* __restrict__ SH, const int* __restrict__ cnt, int r0base)
{
    __shared__ unsigned int sHist[4][256];
    __shared__ unsigned int sWsum[4];
    __shared__ float sRed[8];
    __shared__ unsigned int sPrefix, sRemain;

    const int b = blockIdx.y;
    const int lr = blockIdx.x;
    if (r0base + lr >= cnt[b]) return;
    const int t = threadIdx.x, lane = t & 63, wid = t >> 6;

    uint4* row = (uint4*)(SH + ((size_t)b * QR + lr) * N_);
    uint4 rv[2];
    rv[0] = row[t];
    rv[1] = row[t + 256];

    float sv[16];
    unsigned int mu[16];
#pragma unroll
    for (int q = 0; q < 2; ++q) {
        const unsigned int* pu = (const unsigned int*)&rv[q];
#pragma unroll
        for (int dw = 0; dw < 4; ++dw) {
            unsigned int u = pu[dw];
            unsigned short h0 = (unsigned short)(u & 0xffffu);
            unsigned short h1 = (unsigned short)(u >> 16);
            int e = q * 8 + dw * 2;
            sv[e]     = h2f(h0);
            sv[e + 1] = h2f(h1);
            mu[e]     = (h0 & 0x8000u) ? (unsigned int)((~h0) & 0xffffu)
                                       : (unsigned int)(h0 | 0x8000u);
            mu[e + 1] = (h1 & 0x8000u) ? (unsigned int)((~h1) & 0xffffu)
                                       : (unsigned int)(h1 | 0x8000u);
        }
    }

    float m = -3.4e38f;
#pragma unroll
    for (int e = 0; e < 16; ++e) m = fmaxf(m, sv[e]);
#pragma unroll
    for (int off = 32; off > 0; off >>= 1) m = fmaxf(m, __shfl_xor(m, off));
    if (lane == 0) sRed[wid] = m;
    __syncthreads();
    m = fmaxf(fmaxf(sRed[0], sRed[1]), fmaxf(sRed[2], sRed[3]));

    unsigned int prefix = 0u;
    unsigned int remain = KSEL;
    for (int d = 1; d >= 0; --d) {
        __syncthreads();
#pragma unroll
        for (int ww = 0; ww < 4; ++ww) sHist[ww][t] = 0u;
        __syncthreads();
#pragma unroll
        for (int e = 0; e < 16; ++e) {
            if ((mu[e] >> (8 * (d + 1))) == prefix)
                atomicAdd(&sHist[wid][(mu[e] >> (8 * d)) & 255u], 1u);
        }
        __syncthreads();
        unsigned int x = sHist[0][t] + sHist[1][t] + sHist[2][t] + sHist[3][t];
        unsigned int own = x;
#pragma unroll
        for (int off = 1; off < 64; off <<= 1) {
            unsigned int y = __shfl_down(x, off);
            if (lane + off < 64) x += y;
        }
        if (lane == 0) sWsum[wid] = x;
        __syncthreads();
        for (int ww = wid + 1; ww < 4; ++ww) x += sWsum[ww];
        unsigned int nxt = x - own;
        if (x >= remain && nxt < remain) {
            sPrefix = (prefix << 8) | (unsigned int)t;
            sRemain = remain - nxt;
        }
        __syncthreads();
        prefix = sPrefix;
        remain = sRemain;
    }
    const unsigned int tu = prefix;

    float z = 0.f, ssel = 0.f;
#pragma unroll
    for (int e = 0; e < 16; ++e) {
        float ex = expf(sv[e] - m);
        z += ex;
        if (mu[e] >= tu) ssel += ex;
    }
#pragma unroll
    for (int off = 32; off > 0; off >>= 1) {
        z    += __shfl_xor(z, off);
        ssel += __shfl_xor(ssel, off);
    }
    __syncthreads();
    if (lane == 0) { sRed[wid] = z; sRed[4 + wid] = ssel; }
    __syncthreads();
    const float zt = sRed[0] + sRed[1] + sRed[2] + sRed[3];
    const float st = sRed[4] + sRed[5] + sRed[6] + sRed[7];
    const float inv = 1.f / (st + 1e-6f * zt);

#pragma unroll
    for (int q = 0; q < 2; ++q) {
        unsigned int* pu = (unsigned int*)&rv[q];
#pragma unroll
        for (int dw = 0; dw < 4; ++dw) {
            int e = q * 8 + dw * 2;
            unsigned int p0 = (mu[e] >= tu) ? (unsigned int)f2h(expf(sv[e] - m) * inv) : 0u;
            unsigned int p1 = (mu[e + 1] >= tu) ? (unsigned int)f2h(expf(sv[e + 1] - m) * inv) : 0u;
            pu[dw] = p0 | (p1 << 16);
        }
    }
    row[t]       = rv[0];
    row[t + 256] = rv[1];
}

// ---------------------------------------------------------------------------
// pv (MFMA f16, split-K=8): gc_part[b][ks][lr][i] over j in ks*512..+512.
// A = gWT-rows (i), B = P-rows (r) -> float4 stores along i.
// grid (QR/64, 8, B)
// ---------------------------------------------------------------------------
__global__ __launch_bounds__(256) void pv_kernel(
    const unsigned short* __restrict__ SH, const unsigned short* __restrict__ gWTH,
    const int* __restrict__ cnt, float* __restrict__ gc_part, int r0base)
{
    __shared__ unsigned short Pt[64][72];
    __shared__ unsigned short Gt[128][72];

    const int b = blockIdx.z;
    const int count = cnt[b];
    const int lr0 = blockIdx.x * 64;
    if (r0base + lr0 >= count) return;
    const int ks = blockIdx.y;
    const int t = threadIdx.x;
    const int w = t >> 6, lane = t & 63;
    const int lrow = lane & 15, lk = (lane >> 4) * 8;
    const int wiA = (w & 1) * 64, wrB = (w >> 1) * 32;

    f32x4 acc[4][2];
#pragma unroll
    for (int u = 0; u < 4; ++u)
#pragma unroll
        for (int v = 0; v < 2; ++v) acc[u][v] = (f32x4)(0.f);

    for (int jc = ks * 512; jc < ks * 512 + 512; jc += 64) {
        __syncthreads();
#pragma unroll
        for (int s = 0; s < 2; ++s) {
            int e4 = t + 256 * s;             // 512 x 16B
            int r = e4 >> 3, k8 = e4 & 7;
            *(float4*)&Pt[r][k8 * 8] =
                *(const float4*)&SH[((size_t)b * QR + lr0 + r) * N_ + jc + k8 * 8];
        }
#pragma unroll
        for (int s = 0; s < 4; ++s) {
            int e4 = t + 256 * s;             // 1024 x 16B
            int i = e4 >> 3, k8 = e4 & 7;
            *(float4*)&Gt[i][k8 * 8] =
                *(const float4*)&gWTH[((size_t)b * IC_ + i) * N_ + jc + k8 * 8];
        }
        __syncthreads();

#pragma unroll
        for (int kstep = 0; kstep < 2; ++kstep) {
            const int kk = kstep * 32 + lk;
            f16x8 af[4], bf[2];
#pragma unroll
            for (int u = 0; u < 4; ++u)
                af[u] = *(const f16x8*)&Gt[wiA + u * 16 + lrow][kk];
#pragma unroll
            for (int v = 0; v < 2; ++v)
                bf[v] = *(const f16x8*)&Pt[wrB + v * 16 + lrow][kk];
#pragma unroll
            for (int u = 0; u < 4; ++u)
#pragma unroll
                for (int v = 0; v < 2; ++v)
                    acc[u][v] = __builtin_amdgcn_mfma_f32_16x16x32_f16(
                        af[u], bf[v], acc[u][v], 0, 0, 0);
        }
    }

    const int crow = (lane >> 4) * 4;
#pragma unroll
    for (int u = 0; u < 4; ++u) {
        const int ib = wiA + u * 16 + crow;
#pragma unroll
        for (int v = 0; v < 2; ++v) {
            const int r = lr0 + wrB + v * 16 + lrow;
            *(float4*)&gc_part[(((size_t)b * KS_PV + ks) * QR + r) * IC_ + ib] =
                make_float4(acc[u][v][0], acc[u][v][1], acc[u][v][2], acc[u][v][3]);
        }
    }
}

// ---------------------------------------------------------------------------
// reduce split-K partials, ReLU, scatter to gc[b][n][i]. grid (QR*IC/256, B)
// ---------------------------------------------------------------------------
__global__ __launch_bounds__(256) void scatter_kernel(
    const float* __restrict__ gc_part, const int* __restrict__ cnt,
    const int* __restrict__ list, float* __restrict__ gc, int r0base)
{
    const int b = blockIdx.y;
    int idx = blockIdx.x * 256 + threadIdx.x;
    int lr = idx >> 7, i = idx & 127;
    if (r0base + lr >= cnt[b]) return;
    float v = 0.f;
#pragma unroll
    for (int ks = 0; ks < KS_PV; ++ks)
        v += gc_part[(((size_t)b * KS_PV + ks) * QR + lr) * IC_ + i];
    int n = list[b * N_ + r0base + lr];
    gc[((size_t)b * N_ + n) * IC_ + i] = fmaxf(v, 0.f);
}

// ---------------------------------------------------------------------------
// y[b,c,n] = Wout[c,:] . gc[b,n,:] + bout[c].  64c x 64n tiles.
// ---------------------------------------------------------------------------
__global__ __launch_bounds__(256) void y_kernel(
    const float* __restrict__ gc, const float* __restrict__ Wout,
    const float* __restrict__ bout, float* __restrict__ y)
{
    __shared__ float Wt[64][33];
    __shared__ float Gt[32][68];
    const int n0 = blockIdx.x * 64;
    const int c0 = blockIdx.y * 64;
    const int b  = blockIdx.z;
    const int t = threadIdx.x;
    const int tx = t & 15, ty = t >> 4;

    float acc[4][4];
#pragma unroll
    for (int u = 0; u < 4; ++u)
#pragma unroll
        for (int v = 0; v < 4; ++v) acc[u][v] = 0.f;

    for (int kc = 0; kc < IC_; kc += 32) {
        __syncthreads();
#pragma unroll
        for (int s = 0; s < 2; ++s) {
            int e4 = t + 256 * s;
            int c = e4 >> 3, k4 = e4 & 7;
            float4 ww = *(const float4*)&Wout[(size_t)(c0 + c) * IC_ + kc + k4 * 4];
            Wt[c][k4 * 4 + 0] = ww.x; Wt[c][k4 * 4 + 1] = ww.y;
            Wt[c][k4 * 4 + 2] = ww.z; Wt[c][k4 * 4 + 3] = ww.w;
        }
#pragma unroll
        for (int s = 0; s < 2; ++s) {
            int e4 = t + 256 * s;
            int nn = e4 >> 3, k4 = e4 & 7;
            float4 g = *(const float4*)&gc[((size_t)b * N_ + n0 + nn) * IC_ + kc + k4 * 4];
            Gt[k4 * 4 + 0][nn] = g.x; Gt[k4 * 4 + 1][nn] = g.y;
            Gt[k4 * 4 + 2][nn] = g.z; Gt[k4 * 4 + 3][nn] = g.w;
        }
        __syncthreads();

#pragma unroll 4
        for (int k = 0; k < 32; ++k) {
            float a[4];
#pragma unroll
            for (int u = 0; u < 4; ++u) a[u] = Wt[ty * 4 + u][k];
            const float4 g4 = *(const float4*)&Gt[k][tx * 4];
            const float gm[4] = {g4.x, g4.y, g4.z, g4.w};
#pragma unroll
            for (int u = 0; u < 4; ++u)
#pragma unroll
                for (int v = 0; v < 4; ++v)
                    acc[u][v] = fmaf(a[u], gm[v], acc[u][v]);
        }
    }

#pragma unroll
    for (int u = 0; u < 4; ++u) {
        const int c = c0 + ty * 4 + u;
        const float bo = bout[c];
        *(float4*)&y[((size_t)b * C_ + c) * N_ + n0 + tx * 4] =
            make_float4(acc[u][0] + bo, acc[u][1] + bo,
                        acc[u][2] + bo, acc[u][3] + bo);
    }
}

// ---------------------------------------------------------------------------
// BatchNorm stats per channel
// ---------------------------------------------------------------------------
__global__ __launch_bounds__(256) void bn_stats_kernel(
    const float* __restrict__ y, float* __restrict__ mean,
    float* __restrict__ rsig)
{
    __shared__ float sr[8];
    const int c = blockIdx.x, t = threadIdx.x;
    const int lane = t & 63, wid = t >> 6;
    float s = 0.f, ss = 0.f;
    for (int b = 0; b < B_; ++b) {
        const float* yr = y + ((size_t)b * C_ + c) * N_;
        for (int n = t; n < N_; n += 256) {
            float v = yr[n];
            s += v; ss = fmaf(v, v, ss);
        }
    }
#pragma unroll
    for (int off = 32; off > 0; off >>= 1) {
        s  += __shfl_xor(s, off);
        ss += __shfl_xor(ss, off);
    }
    if (lane == 0) { sr[wid] = s; sr[4 + wid] = ss; }
    __syncthreads();
    if (t == 0) {
        float st  = sr[0] + sr[1] + sr[2] + sr[3];
        float sst = sr[4] + sr[5] + sr[6] + sr[7];
        float mu  = st / (float)(B_ * N_);
        float var = sst / (float)(B_ * N_) - mu * mu;
        mean[c] = mu;
        rsig[c] = rsqrtf(var + 1e-5f);
    }
}

// ---------------------------------------------------------------------------
// out = x + gamma*(y-mean)*rsig + beta
// ---------------------------------------------------------------------------
__global__ __launch_bounds__(256) void final_kernel(
    const float* __restrict__ x, const float* __restrict__ y,
    const float* __restrict__ mean, const float* __restrict__ rsig,
    const float* __restrict__ gamma, const float* __restrict__ beta,
    float* __restrict__ out)
{
    int idx = blockIdx.x * 256 + threadIdx.x;
    if (idx >= B_ * C_ * N_) return;
    int c = (idx >> 12) & (C_ - 1);
    out[idx] = x[idx] + fmaf(gamma[c], (y[idx] - mean[c]) * rsig[c], beta[c]);
}

extern "C" void kernel_launch(void* const* d_in, const int* in_sizes, int n_in,
                              void* d_out, int out_size, void* d_ws, size_t ws_size,
                              hipStream_t stream)
{
    const float* x     = (const float*)d_in[0];
    const float* hard  = (const float*)d_in[1];
    const float* Wg    = (const float*)d_in[2];
    const float* bg    = (const float*)d_in[3];
    const float* Wth   = (const float*)d_in[4];
    const float* bth   = (const float*)d_in[5];
    const float* Wph   = (const float*)d_in[6];
    const float* bph   = (const float*)d_in[7];
    const float* Wgcn  = (const float*)d_in[8];
    const float* Wout  = (const float*)d_in[9];
    const float* bout  = (const float*)d_in[10];
    const float* gamma = (const float*)d_in[11];
    const float* beta  = (const float*)d_in[12];
    float* out = (float*)d_out;
    float* ws  = (float*)d_ws;

    float* gc    = ws + OFF_GC;
    float* y     = ws + OFF_Y;
    float* Weff  = ws + OFF_WEFF;
    float* beff  = ws + OFF_BEFF;
    float* mean  = ws + OFF_MEAN;
    float* rsig  = ws + OFF_RSIG;
    int*   cnt   = (int*)(ws + OFF_CNT);
    int*   list  = (int*)(ws + OFF_LIST);
    unsigned short* thetaH = (unsigned short*)(ws + OFF_THB);
    unsigned short* phiH   = (unsigned short*)(ws + OFF_PHB);
    unsigned short* gWTH   = (unsigned short*)(ws + OFF_GWT);
    unsigned short* xTH    = (unsigned short*)(ws + OFF_XTH);
    unsigned short* WallH  = (unsigned short*)(ws + OFF_WALL);
    float* ball  = ws + OFF_BALL;
    unsigned short* SH = (unsigned short*)(ws + OFF_S);
    float* gc_part = out;   // d_out (8 MB = B*KS_PV*QR*IC*4) as split-K
                            // scratch; fully overwritten by final_kernel.

    hipMemsetAsync(gc, 0, (size_t)B_ * N_ * IC_ * sizeof(float), stream);

    weff_kernel<<<dim3(IC_), 256, 0, stream>>>(Wg, bg, Wgcn, Weff, beff);
    wconv_kernel<<<dim3(384), 256, 0, stream>>>(
        Wth, bth, Weff, beff, Wph, bph, WallH, ball);
    xt_kernel<<<dim3(N_ / 64, C_ / 64, B_), 256, 0, stream>>>(x, xTH);
    proj_kernel<<<dim3(N_ / 128, 3, B_), 256, 0, stream>>>(
        xTH, WallH, ball, thetaH, gWTH, phiH);
    compact_kernel<<<dim3(B_), 1024, 0, stream>>>(hard, cnt, list);

    for (int r0 = 0; r0 < N_; r0 += QR) {
        score_kernel<<<dim3(N_ / 128, QR / 128, B_), 256, 0, stream>>>(
            thetaH, phiH, cnt, list, SH, r0);
        select_kernel<<<dim3(QR, B_), 256, 0, stream>>>(SH, cnt, r0);
        pv_kernel<<<dim3(QR / 64, KS_PV, B_), 256, 0, stream>>>(
            SH, gWTH, cnt, gc_part, r0);
        scatter_kernel<<<dim3(QR * IC_ / 256, B_), 256, 0, stream>>>(
            gc_part, cnt, list, gc, r0);
    }

    y_kernel<<<dim3(N_ / 64, C_ / 64, B_), 256, 0, stream>>>(gc, Wout, bout, y);
    bn_stats_kernel<<<dim3(C_), 256, 0, stream>>>(y, mean, rsig);
    final_kernel<<<dim3(B_ * C_ * N_ / 256), 256, 0, stream>>>(
        x, y, mean, rsig, gamma, beta, out);
}

// Round 12
// 141.463 us; speedup vs baseline: 2.7945x; 1.5071x over previous
//
#include <hip/hip_runtime.h>

#define B_ 2
#define C_ 256
#define IC_ 128
#define N_ 4096
#define KSEL 2048
#define KS_PV 8

// fixed workspace offsets (floats); SH + gc_part sized at runtime
#define OFF_GC    0u          // gc f32 [B][N][IC]            4 MB
#define OFF_Y     1048576u    // y  f32 [B][C][N]             8 MB
#define OFF_MEAN  3145728u
#define OFF_RSIG  3145984u
#define OFF_CNT   3146240u
#define OFF_LIST  3146304u    // int[B*N]
#define OFF_THB   3154496u    // theta f16 [B][N][IC]         2 MB
#define OFF_PHB   3678784u    // phi   f16 [B][N][IC]         2 MB
#define OFF_GWT   4203072u    // gW^T  f16 [B][IC][N]         2 MB
#define OFF_XTH   4727360u    // x^T   f16 [B][N][C]          4 MB
#define OFF_WALL  5775936u    // {Wth,Weff,Wph} f16 [384][256]
#define OFF_BALL  5825088u    // f32 [384]
#define OFF_S     5825472u    // SH f16 [B][qr][N] ; then gc_part f32

typedef __attribute__((ext_vector_type(8))) _Float16 f16x8;
typedef __attribute__((ext_vector_type(4))) float f32x4;

__device__ __forceinline__ unsigned short f2h(float f) {
    union { _Float16 h; unsigned short u; } cv;
    cv.h = (_Float16)f;
    return cv.u;
}
__device__ __forceinline__ float h2f(unsigned short u) {
    union { unsigned short u; _Float16 h; } cv;
    cv.u = u;
    return (float)cv.h;
}

// ---------------------------------------------------------------------------
// pack {Wth, Wgcn^T.Wg (computed inline), Wph} -> WallH f16 [384][256] + ball
// ---------------------------------------------------------------------------
__global__ __launch_bounds__(256) void wconv_kernel(
    const float* __restrict__ Wth, const float* __restrict__ bth,
    const float* __restrict__ Wg,  const float* __restrict__ bg,
    const float* __restrict__ Wgcn,
    const float* __restrict__ Wph, const float* __restrict__ bph,
    unsigned short* __restrict__ WallH, float* __restrict__ ball)
{
    const int o = blockIdx.x;          // 0..383
    const int c = threadIdx.x;         // 0..255
    const int oo = o & 127;
    float wv, bv;
    if (o < 128) {
        wv = Wth[oo * C_ + c];
        bv = bth[oo];
    } else if (o < 256) {
        float acc = 0.f;
        for (int i = 0; i < IC_; ++i)
            acc = fmaf(Wgcn[i * IC_ + oo], Wg[i * C_ + c], acc);
        wv = acc;
        float bacc = 0.f;
        for (int i = 0; i < IC_; ++i)
            bacc = fmaf(Wgcn[i * IC_ + oo], bg[i], bacc);
        bv = bacc;
    } else {
        wv = Wph[oo * C_ + c];
        bv = bph[oo];
    }
    WallH[o * C_ + c] = f2h(wv);
    if (c == 0) ball[o] = bv;
}

// ---------------------------------------------------------------------------
// xT: x [b][c][n] f32 -> xTH [b][n][c] f16.  64x64 LDS transpose tiles.
// grid (N/64, C/64, B)
// ---------------------------------------------------------------------------
__global__ __launch_bounds__(256) void xt_kernel(
    const float* __restrict__ x, unsigned short* __restrict__ xTH)
{
    __shared__ float Xs[64][65];
    const int n0 = blockIdx.x * 64, c0 = blockIdx.y * 64, b = blockIdx.z;
    const int t = threadIdx.x;
#pragma unroll
    for (int s = 0; s < 4; ++s) {
        int e4 = t + 256 * s;            // 1024 float4 = 64c x 16(n/4)
        int cc = e4 >> 4, c4 = e4 & 15;
        float4 v = *(const float4*)&x[((size_t)b * C_ + c0 + cc) * N_ + n0 + c4 * 4];
        Xs[cc][c4 * 4 + 0] = v.x; Xs[cc][c4 * 4 + 1] = v.y;
        Xs[cc][c4 * 4 + 2] = v.z; Xs[cc][c4 * 4 + 3] = v.w;
    }
    __syncthreads();
#pragma unroll
    for (int s = 0; s < 4; ++s) {
        int e = t + 256 * s;             // 1024 ushort4 = 64n x 16(c/4)
        int nn = e >> 4, c4 = e & 15;
        ushort4 h;
        h.x = f2h(Xs[c4 * 4 + 0][nn]);
        h.y = f2h(Xs[c4 * 4 + 1][nn]);
        h.z = f2h(Xs[c4 * 4 + 2][nn]);
        h.w = f2h(Xs[c4 * 4 + 3][nn]);
        *(ushort4*)&xTH[((size_t)b * N_ + n0 + nn) * C_ + c0 + c4 * 4] = h;
    }
}

// ---------------------------------------------------------------------------
// proj (MFMA f16): out[o][n] = WallH[pj-chunk] . xT, K=256.
// 128o x 128n tile, 4 waves. pj 0->thetaH[n][o], 1->gWTH[o][n], 2->phiH[n][o]
// grid (N/128, 3, B)
// ---------------------------------------------------------------------------
__global__ __launch_bounds__(256) void proj_kernel(
    const unsigned short* __restrict__ xTH,
    const unsigned short* __restrict__ WallH, const float* __restrict__ ball,
    unsigned short* __restrict__ thetaH, unsigned short* __restrict__ gWTH,
    unsigned short* __restrict__ phiH)
{
    __shared__ unsigned short Xt[128][72];
    __shared__ unsigned short Wt[128][72];
    const int n0 = blockIdx.x * 128;
    const int pj = blockIdx.y;
    const int b  = blockIdx.z;
    const int t = threadIdx.x, w = t >> 6, lane = t & 63;
    const int lrow = lane & 15, lk = (lane >> 4) * 8;
    const int wA = (w >> 1) * 64, wB = (w & 1) * 64;

    f32x4 acc[4][4];
#pragma unroll
    for (int u = 0; u < 4; ++u)
#pragma unroll
        for (int v = 0; v < 4; ++v) acc[u][v] = (f32x4)(0.f);

    for (int kc = 0; kc < C_; kc += 64) {
        __syncthreads();
#pragma unroll
        for (int s = 0; s < 4; ++s) {
            int e4 = t + 256 * s;        // 1024 x 16B
            int r = e4 >> 3, k8 = e4 & 7;
            *(float4*)&Xt[r][k8 * 8] =
                *(const float4*)&xTH[((size_t)b * N_ + n0 + r) * C_ + kc + k8 * 8];
        }
#pragma unroll
        for (int s = 0; s < 4; ++s) {
            int e4 = t + 256 * s;
            int r = e4 >> 3, k8 = e4 & 7;
            *(float4*)&Wt[r][k8 * 8] =
                *(const float4*)&WallH[(size_t)(pj * 128 + r) * C_ + kc + k8 * 8];
        }
        __syncthreads();

#pragma unroll
        for (int kstep = 0; kstep < 2; ++kstep) {
            const int kk = kstep * 32 + lk;
            f16x8 af[4], bf[4];
            if (pj != 1) {               // A = W (o), B = xT (n)
#pragma unroll
                for (int u = 0; u < 4; ++u)
                    af[u] = *(const f16x8*)&Wt[wA + u * 16 + lrow][kk];
#pragma unroll
                for (int v = 0; v < 4; ++v)
                    bf[v] = *(const f16x8*)&Xt[wB + v * 16 + lrow][kk];
            } else {                     // A = xT (n), B = W (o)
#pragma unroll
                for (int u = 0; u < 4; ++u)
                    af[u] = *(const f16x8*)&Xt[wA + u * 16 + lrow][kk];
#pragma unroll
                for (int v = 0; v < 4; ++v)
                    bf[v] = *(const f16x8*)&Wt[wB + v * 16 + lrow][kk];
            }
#pragma unroll
            for (int u = 0; u < 4; ++u)
#pragma unroll
                for (int v = 0; v < 4; ++v)
                    acc[u][v] = __builtin_amdgcn_mfma_f32_16x16x32_f16(
                        af[u], bf[v], acc[u][v], 0, 0, 0);
        }
    }

    const int crow = (lane >> 4) * 4;
    if (pj != 1) {
        unsigned short* dst = (pj == 0) ? thetaH : phiH;
        const int bb2 = (pj == 0) ? 0 : 256;
#pragma unroll
        for (int u = 0; u < 4; ++u) {
            const int ob = wA + u * 16 + crow;
            float b0 = ball[bb2 + ob + 0], b1 = ball[bb2 + ob + 1];
            float b2 = ball[bb2 + ob + 2], b3 = ball[bb2 + ob + 3];
#pragma unroll
            for (int v = 0; v < 4; ++v) {
                const int n = n0 + wB + v * 16 + lrow;
                ushort4 h;
                h.x = f2h(acc[u][v][0] + b0);
                h.y = f2h(acc[u][v][1] + b1);
                h.z = f2h(acc[u][v][2] + b2);
                h.w = f2h(acc[u][v][3] + b3);
                *(ushort4*)&dst[((size_t)b * N_ + n) * IC_ + ob] = h;
            }
        }
    } else {
#pragma unroll
        for (int v = 0; v < 4; ++v) {
            const int o = wB + v * 16 + lrow;
            const float bo = ball[128 + o];
#pragma unroll
            for (int u = 0; u < 4; ++u) {
                const int nb = n0 + wA + u * 16 + crow;
                ushort4 h;
                h.x = f2h(acc[u][v][0] + bo);
                h.y = f2h(acc[u][v][1] + bo);
                h.z = f2h(acc[u][v][2] + bo);
                h.w = f2h(acc[u][v][3] + bo);
                *(ushort4*)&gWTH[((size_t)b * IC_ + o) * N_ + nb] = h;
            }
        }
    }
}

// ---------------------------------------------------------------------------
// hard-row compaction — atomic-free block scan. One block per batch.
// ---------------------------------------------------------------------------
__global__ __launch_bounds__(1024) void compact_kernel(
    const float* __restrict__ hard_map, int* __restrict__ cnt,
    int* __restrict__ list)
{
    __shared__ int wsum[16];
    const int b = blockIdx.x;
    const int t = threadIdx.x, lane = t & 63, wid = t >> 6;
    const float* hm = hard_map + (size_t)b * N_;

    float4 v = *(const float4*)&hm[t * 4];
    int f0 = v.x > 0.5f, f1 = v.y > 0.5f, f2 = v.z > 0.5f, f3 = v.w > 0.5f;
    const int c = f0 + f1 + f2 + f3;

    int x = c;
#pragma unroll
    for (int off = 1; off < 64; off <<= 1) {
        int y = __shfl_up(x, off);
        if (lane >= off) x += y;
    }
    if (lane == 63) wsum[wid] = x;
    __syncthreads();
    int base = 0;
    for (int ww = 0; ww < wid; ++ww) base += wsum[ww];
    int pos = base + x - c;

    int* lst = list + b * N_;
    int n = t * 4;
    if (f0) lst[pos++] = n;
    if (f1) lst[pos++] = n + 1;
    if (f2) lst[pos++] = n + 2;
    if (f3) lst[pos++] = n + 3;

    if (t == 0) {
        int tot = 0;
#pragma unroll
        for (int ww = 0; ww < 16; ++ww) tot += wsum[ww];
        cnt[b] = tot;
    }
}

// ---------------------------------------------------------------------------
// score (MFMA f16): SH[b][lr][m] = theta_row(lr) . phi[:,m], f16 out.
// grid (N/128, qr/128, B)
// ---------------------------------------------------------------------------
__global__ __launch_bounds__(256) void score_kernel(
    const unsigned short* __restrict__ thetaH,
    const unsigned short* __restrict__ phiH,
    const int* __restrict__ cnt, const int* __restrict__ list,
    unsigned short* __restrict__ SH, int r0base, int qr)
{
    __shared__ unsigned short Th[128][136];
    __shared__ unsigned short Ph[128][136];
    __shared__ int sIdx[128];

    const int b = blockIdx.z;
    const int count = cnt[b];
    const int lr0 = blockIdx.y * 128;
    if (r0base + lr0 >= count) return;
    const int m0 = blockIdx.x * 128;
    const int t = threadIdx.x;
    const int w = t >> 6, lane = t & 63;

    if (t < 128) {
        int gr = r0base + lr0 + t;
        sIdx[t] = (gr < count) ? list[b * N_ + gr] : -1;
    }
    __syncthreads();

#pragma unroll
    for (int s = 0; s < 8; ++s) {
        int e4 = t + 256 * s;
        int r = e4 >> 4, k4 = e4 & 15;
        int gr = sIdx[r];
        float4 v = make_float4(0.f, 0.f, 0.f, 0.f);
        if (gr >= 0)
            v = *(const float4*)&thetaH[((size_t)b * N_ + gr) * IC_ + k4 * 8];
        *(float4*)&Th[r][k4 * 8] = v;
    }
#pragma unroll
    for (int s = 0; s < 8; ++s) {
        int e4 = t + 256 * s;
        int r = e4 >> 4, k4 = e4 & 15;
        *(float4*)&Ph[r][k4 * 8] =
            *(const float4*)&phiH[((size_t)b * N_ + m0 + r) * IC_ + k4 * 8];
    }
    __syncthreads();

    const int wm = (w >> 1) * 64, wr = (w & 1) * 64;
    const int lrow = lane & 15, lk = (lane >> 4) * 8;

    f32x4 acc[4][4];
#pragma unroll
    for (int u = 0; u < 4; ++u)
#pragma unroll
        for (int v = 0; v < 4; ++v) acc[u][v] = (f32x4)(0.f);

#pragma unroll
    for (int ks = 0; ks < 4; ++ks) {
        const int kk = ks * 32 + lk;
        f16x8 af[4], bf[4];
#pragma unroll
        for (int u = 0; u < 4; ++u)
            af[u] = *(const f16x8*)&Ph[wm + u * 16 + lrow][kk];
#pragma unroll
        for (int v = 0; v < 4; ++v)
            bf[v] = *(const f16x8*)&Th[wr + v * 16 + lrow][kk];
#pragma unroll
        for (int u = 0; u < 4; ++u)
#pragma unroll
            for (int v = 0; v < 4; ++v)
                acc[u][v] = __builtin_amdgcn_mfma_f32_16x16x32_f16(
                    af[u], bf[v], acc[u][v], 0, 0, 0);
    }

    const int crow = (lane >> 4) * 4;
#pragma unroll
    for (int u = 0; u < 4; ++u) {
        const int mb = m0 + wm + u * 16 + crow;
#pragma unroll
        for (int v = 0; v < 4; ++v) {
            const int r = lr0 + wr + v * 16 + lrow;
            ushort4 h;
            h.x = f2h(acc[u][v][0]);
            h.y = f2h(acc[u][v][1]);
            h.z = f2h(acc[u][v][2]);
            h.w = f2h(acc[u][v][3]);
            *(ushort4*)&SH[((size_t)b * qr + r) * N_ + mb] = h;
        }
    }
}

// ---------------------------------------------------------------------------
// select: exact kth-largest radix select (2x8-bit passes on monotone u16)
// + softmax; writes P f16 in place. grid (qr, B)
// ---------------------------------------------------------------------------
__global__ __launch_bounds__(256) void select_kernel(
    unsigned short* __restrict__ SH, const int* __restrict__ cnt,
    int r0base, int qr)
{
    __shared__ unsigned int sHist[4][256];
    __shared__ unsigned int sWsum[4];
    __shared__ float sRed[8];
    __shared__ unsigned int sPrefix, sRemain;

    const int b = blockIdx.y;
    const int lr = blockIdx.x;
    if (r0base + lr >= cnt[b]) return;
    const int t = threadIdx.x, lane = t & 63, wid = t >> 6;

    uint4* row = (uint4*)(SH + ((size_t)b * qr + lr) * N_);
    uint4 rv[2];
    rv[0] = row[t];
    rv[1] = row[t + 256];

    float sv[16];
    unsigned int mu[16];
#pragma unroll
    for (int q = 0; q < 2; ++q) {
        const unsigned int* pu = (const unsigned int*)&rv[q];
#pragma unroll
        for (int dw = 0; dw < 4; ++dw) {
            unsigned int u = pu[dw];
            unsigned short h0 = (unsigned short)(u & 0xffffu);
            unsigned short h1 = (unsigned short)(u >> 16);
            int e = q * 8 + dw * 2;
            sv[e]     = h2f(h0);
            sv[e + 1] = h2f(h1);
            mu[e]     = (h0 & 0x8000u) ? (unsigned int)((~h0) & 0xffffu)
                                       : (unsigned int)(h0 | 0x8000u);
            mu[e + 1] = (h1 & 0x8000u) ? (unsigned int)((~h1) & 0xffffu)
                                       : (unsigned int)(h1 | 0x8000u);
        }
    }

    float m = -3.4e38f;
#pragma unroll
    for (int e = 0; e < 16; ++e) m = fmaxf(m, sv[e]);
#pragma unroll
    for (int off = 32; off > 0; off >>= 1) m = fmaxf(m, __shfl_xor(m, off));
    if (lane == 0) sRed[wid] = m;
    __syncthreads();
    m = fmaxf(fmaxf(sRed[0], sRed[1]), fmaxf(sRed[2], sRed[3]));

    unsigned int prefix = 0u;
    unsigned int remain = KSEL;
    for (int d = 1; d >= 0; --d) {
        __syncthreads();
#pragma unroll
        for (int ww = 0; ww < 4; ++ww) sHist[ww][t] = 0u;
        __syncthreads();
#pragma unroll
        for (int e = 0; e < 16; ++e) {
            if ((mu[e] >> (8 * (d + 1))) == prefix)
                atomicAdd(&sHist[wid][(mu[e] >> (8 * d)) & 255u], 1u);
        }
        __syncthreads();
        unsigned int x = sHist[0][t] + sHist[1][t] + sHist[2][t] + sHist[3][t];
        unsigned int own = x;
#pragma unroll
        for (int off = 1; off < 64; off <<= 1) {
            unsigned int y = __shfl_down(x, off);
            if (lane + off < 64) x += y;
        }
        if (lane == 0) sWsum[wid] = x;
        __syncthreads();
        for (int ww = wid + 1; ww < 4; ++ww) x += sWsum[ww];
        unsigned int nxt = x - own;
        if (x >= remain && nxt < remain) {
            sPrefix = (prefix << 8) | (unsigned int)t;
            sRemain = remain - nxt;
        }
        __syncthreads();
        prefix = sPrefix;
        remain = sRemain;
    }
    const unsigned int tu = prefix;

    float z = 0.f, ssel = 0.f;
#pragma unroll
    for (int e = 0; e < 16; ++e) {
        float ex = expf(sv[e] - m);
        z += ex;
        if (mu[e] >= tu) ssel += ex;
    }
#pragma unroll
    for (int off = 32; off > 0; off >>= 1) {
        z    += __shfl_xor(z, off);
        ssel += __shfl_xor(ssel, off);
    }
    __syncthreads();
    if (lane == 0) { sRed[wid] = z; sRed[4 + wid] = ssel; }
    __syncthreads();
    const float zt = sRed[0] + sRed[1] + sRed[2] + sRed[3];
    const float st = sRed[4] + sRed[5] + sRed[6] + sRed[7];
    const float inv = 1.f / (st + 1e-6f * zt);

#pragma unroll
    for (int q = 0; q < 2; ++q) {
        unsigned int* pu = (unsigned int*)&rv[q];
#pragma unroll
        for (int dw = 0; dw < 4; ++dw) {
            int e = q * 8 + dw * 2;
            unsigned int p0 = (mu[e] >= tu) ? (unsigned int)f2h(expf(sv[e] - m) * inv) : 0u;
            unsigned int p1 = (mu[e + 1] >= tu) ? (unsigned int)f2h(expf(sv[e + 1] - m) * inv) : 0u;
            pu[dw] = p0 | (p1 << 16);
        }
    }
    row[t]       = rv[0];
    row[t + 256] = rv[1];
}

// ---------------------------------------------------------------------------
// pv (MFMA f16, split-K=8): gc_part[b][ks][lr][i] over j in ks*512..+512.
// grid (qr/64, 8, B)
// ---------------------------------------------------------------------------
__global__ __launch_bounds__(256) void pv_kernel(
    const unsigned short* __restrict__ SH, const unsigned short* __restrict__ gWTH,
    const int* __restrict__ cnt, float* __restrict__ gc_part,
    int r0base, int qr)
{
    __shared__ unsigned short Pt[64][72];
    __shared__ unsigned short Gt[128][72];

    const int b = blockIdx.z;
    const int count = cnt[b];
    const int lr0 = blockIdx.x * 64;
    if (r0base + lr0 >= count) return;
    const int ks = blockIdx.y;
    const int t = threadIdx.x;
    const int w = t >> 6, lane = t & 63;
    const int lrow = lane & 15, lk = (lane >> 4) * 8;
    const int wiA = (w & 1) * 64, wrB = (w >> 1) * 32;

    f32x4 acc[4][2];
#pragma unroll
    for (int u = 0; u < 4; ++u)
#pragma unroll
        for (int v = 0; v < 2; ++v) acc[u][v] = (f32x4)(0.f);

    for (int jc = ks * 512; jc < ks * 512 + 512; jc += 64) {
        __syncthreads();
#pragma unroll
        for (int s = 0; s < 2; ++s) {
            int e4 = t + 256 * s;             // 512 x 16B
            int r = e4 >> 3, k8 = e4 & 7;
            *(float4*)&Pt[r][k8 * 8] =
                *(const float4*)&SH[((size_t)b * qr + lr0 + r) * N_ + jc + k8 * 8];
        }
#pragma unroll
        for (int s = 0; s < 4; ++s) {
            int e4 = t + 256 * s;             // 1024 x 16B
            int i = e4 >> 3, k8 = e4 & 7;
            *(float4*)&Gt[i][k8 * 8] =
                *(const float4*)&gWTH[((size_t)b * IC_ + i) * N_ + jc + k8 * 8];
        }
        __syncthreads();

#pragma unroll
        for (int kstep = 0; kstep < 2; ++kstep) {
            const int kk = kstep * 32 + lk;
            f16x8 af[4], bf[2];
#pragma unroll
            for (int u = 0; u < 4; ++u)
                af[u] = *(const f16x8*)&Gt[wiA + u * 16 + lrow][kk];
#pragma unroll
            for (int v = 0; v < 2; ++v)
                bf[v] = *(const f16x8*)&Pt[wrB + v * 16 + lrow][kk];
#pragma unroll
            for (int u = 0; u < 4; ++u)
#pragma unroll
                for (int v = 0; v < 2; ++v)
                    acc[u][v] = __builtin_amdgcn_mfma_f32_16x16x32_f16(
                        af[u], bf[v], acc[u][v], 0, 0, 0);
        }
    }

    const int crow = (lane >> 4) * 4;
#pragma unroll
    for (int u = 0; u < 4; ++u) {
        const int ib = wiA + u * 16 + crow;
#pragma unroll
        for (int v = 0; v < 2; ++v) {
            const int r = lr0 + wrB + v * 16 + lrow;
            *(float4*)&gc_part[(((size_t)b * KS_PV + ks) * qr + r) * IC_ + ib] =
                make_float4(acc[u][v][0], acc[u][v][1], acc[u][v][2], acc[u][v][3]);
        }
    }
}

// ---------------------------------------------------------------------------
// reduce split-K partials, ReLU, scatter to gc[b][n][i]. grid (qr*IC/256, B)
// ---------------------------------------------------------------------------
__global__ __launch_bounds__(256) void scatter_kernel(
    const float* __restrict__ gc_part, const int* __restrict__ cnt,
    const int* __restrict__ list, float* __restrict__ gc,
    int r0base, int qr)
{
    const int b = blockIdx.y;
    int idx = blockIdx.x * 256 + threadIdx.x;
    int lr = idx >> 7, i = idx & 127;
    if (r0base + lr >= cnt[b]) return;
    float v = 0.f;
#pragma unroll
    for (int ks = 0; ks < KS_PV; ++ks)
        v += gc_part[(((size_t)b * KS_PV + ks) * qr + lr) * IC_ + i];
    int n = list[b * N_ + r0base + lr];
    gc[((size_t)b * N_ + n) * IC_ + i] = fmaxf(v, 0.f);
}

// ---------------------------------------------------------------------------
// y[b,c,n] = Wout[c,:] . gc[b,n,:] + bout[c].  64c x 64n tiles.
// ---------------------------------------------------------------------------
__global__ __launch_bounds__(256) void y_kernel(
    const float* __restrict__ gc, const float* __restrict__ Wout,
    const float* __restrict__ bout, float* __restrict__ y)
{
    __shared__ float Wt[64][33];
    __shared__ float Gt[32][68];
    const int n0 = blockIdx.x * 64;
    const int c0 = blockIdx.y * 64;
    const int b  = blockIdx.z;
    const int t = threadIdx.x;
    const int tx = t & 15, ty = t >> 4;

    float acc[4][4];
#pragma unroll
    for (int u = 0; u < 4; ++u)
#pragma unroll
        for (int v = 0; v < 4; ++v) acc[u][v] = 0.f;

    for (int kc = 0; kc < IC_; kc += 32) {
        __syncthreads();
#pragma unroll
        for (int s = 0; s < 2; ++s) {
            int e4 = t + 256 * s;
            int c = e4 >> 3, k4 = e4 & 7;
            float4 ww = *(const float4*)&Wout[(size_t)(c0 + c) * IC_ + kc + k4 * 4];
            Wt[c][k4 * 4 + 0] = ww.x; Wt[c][k4 * 4 + 1] = ww.y;
            Wt[c][k4 * 4 + 2] = ww.z; Wt[c][k4 * 4 + 3] = ww.w;
        }
#pragma unroll
        for (int s = 0; s < 2; ++s) {
            int e4 = t + 256 * s;
            int nn = e4 >> 3, k4 = e4 & 7;
            float4 g = *(const float4*)&gc[((size_t)b * N_ + n0 + nn) * IC_ + kc + k4 * 4];
            Gt[k4 * 4 + 0][nn] = g.x; Gt[k4 * 4 + 1][nn] = g.y;
            Gt[k4 * 4 + 2][nn] = g.z; Gt[k4 * 4 + 3][nn] = g.w;
        }
        __syncthreads();

#pragma unroll 4
        for (int k = 0; k < 32; ++k) {
            float a[4];
#pragma unroll
            for (int u = 0; u < 4; ++u) a[u] = Wt[ty * 4 + u][k];
            const float4 g4 = *(const float4*)&Gt[k][tx * 4];
            const float gm[4] = {g4.x, g4.y, g4.z, g4.w};
#pragma unroll
            for (int u = 0; u < 4; ++u)
#pragma unroll
                for (int v = 0; v < 4; ++v)
                    acc[u][v] = fmaf(a[u], gm[v], acc[u][v]);
        }
    }

#pragma unroll
    for (int u = 0; u < 4; ++u) {
        const int c = c0 + ty * 4 + u;
        const float bo = bout[c];
        *(float4*)&y[((size_t)b * C_ + c) * N_ + n0 + tx * 4] =
            make_float4(acc[u][0] + bo, acc[u][1] + bo,
                        acc[u][2] + bo, acc[u][3] + bo);
    }
}

// ---------------------------------------------------------------------------
// BatchNorm stats per channel
// ---------------------------------------------------------------------------
__global__ __launch_bounds__(256) void bn_stats_kernel(
    const float* __restrict__ y, float* __restrict__ mean,
    float* __restrict__ rsig)
{
    __shared__ float sr[8];
    const int c = blockIdx.x, t = threadIdx.x;
    const int lane = t & 63, wid = t >> 6;
    float s = 0.f, ss = 0.f;
    for (int b = 0; b < B_; ++b) {
        const float* yr = y + ((size_t)b * C_ + c) * N_;
        for (int n = t; n < N_; n += 256) {
            float v = yr[n];
            s += v; ss = fmaf(v, v, ss);
        }
    }
#pragma unroll
    for (int off = 32; off > 0; off >>= 1) {
        s  += __shfl_xor(s, off);
        ss += __shfl_xor(ss, off);
    }
    if (lane == 0) { sr[wid] = s; sr[4 + wid] = ss; }
    __syncthreads();
    if (t == 0) {
        float st  = sr[0] + sr[1] + sr[2] + sr[3];
        float sst = sr[4] + sr[5] + sr[6] + sr[7];
        float mu  = st / (float)(B_ * N_);
        float var = sst / (float)(B_ * N_) - mu * mu;
        mean[c] = mu;
        rsig[c] = rsqrtf(var + 1e-5f);
    }
}

// ---------------------------------------------------------------------------
// out = x + gamma*(y-mean)*rsig + beta
// ---------------------------------------------------------------------------
__global__ __launch_bounds__(256) void final_kernel(
    const float* __restrict__ x, const float* __restrict__ y,
    const float* __restrict__ mean, const float* __restrict__ rsig,
    const float* __restrict__ gamma, const float* __restrict__ beta,
    float* __restrict__ out)
{
    int idx = blockIdx.x * 256 + threadIdx.x;
    if (idx >= B_ * C_ * N_) return;
    int c = (idx >> 12) & (C_ - 1);
    out[idx] = x[idx] + fmaf(gamma[c], (y[idx] - mean[c]) * rsig[c], beta[c]);
}

extern "C" void kernel_launch(void* const* d_in, const int* in_sizes, int n_in,
                              void* d_out, int out_size, void* d_ws, size_t ws_size,
                              hipStream_t stream)
{
    const float* x     = (const float*)d_in[0];
    const float* hard  = (const float*)d_in[1];
    const float* Wg    = (const float*)d_in[2];
    const float* bg    = (const float*)d_in[3];
    const float* Wth   = (const float*)d_in[4];
    const float* bth   = (const float*)d_in[5];
    const float* Wph   = (const float*)d_in[6];
    const float* bph   = (const float*)d_in[7];
    const float* Wgcn  = (const float*)d_in[8];
    const float* Wout  = (const float*)d_in[9];
    const float* bout  = (const float*)d_in[10];
    const float* gamma = (const float*)d_in[11];
    const float* beta  = (const float*)d_in[12];
    float* out = (float*)d_out;
    float* ws  = (float*)d_ws;

    float* gc    = ws + OFF_GC;
    float* y     = ws + OFF_Y;
    float* mean  = ws + OFF_MEAN;
    float* rsig  = ws + OFF_RSIG;
    int*   cnt   = (int*)(ws + OFF_CNT);
    int*   list  = (int*)(ws + OFF_LIST);
    unsigned short* thetaH = (unsigned short*)(ws + OFF_THB);
    unsigned short* phiH   = (unsigned short*)(ws + OFF_PHB);
    unsigned short* gWTH   = (unsigned short*)(ws + OFF_GWT);
    unsigned short* xTH    = (unsigned short*)(ws + OFF_XTH);
    unsigned short* WallH  = (unsigned short*)(ws + OFF_WALL);
    float* ball  = ws + OFF_BALL;
    unsigned short* SH = (unsigned short*)(ws + OFF_S);

    // runtime-adaptive row-block: SH = qr*4096 floats, gc_part = 2048*qr floats
    const size_t wsf = ws_size / sizeof(float);
    int qr;
    float* gc_part;
    if (wsf >= OFF_S + (size_t)4096 * 6144) {            // 124.1 MB
        qr = 4096; gc_part = ws + OFF_S + (size_t)4096 * 4096;
    } else if (wsf >= OFF_S + (size_t)2048 * 6144) {     // 73.8 MB
        qr = 2048; gc_part = ws + OFF_S + (size_t)2048 * 4096;
    } else {                                             // 40.2 MB (proven)
        qr = 1024; gc_part = out;  // d_out scratch; overwritten by final
    }

    hipMemsetAsync(gc, 0, (size_t)B_ * N_ * IC_ * sizeof(float), stream);

    wconv_kernel<<<dim3(384), 256, 0, stream>>>(
        Wth, bth, Wg, bg, Wgcn, Wph, bph, WallH, ball);
    xt_kernel<<<dim3(N_ / 64, C_ / 64, B_), 256, 0, stream>>>(x, xTH);
    proj_kernel<<<dim3(N_ / 128, 3, B_), 256, 0, stream>>>(
        xTH, WallH, ball, thetaH, gWTH, phiH);
    compact_kernel<<<dim3(B_), 1024, 0, stream>>>(hard, cnt, list);

    for (int r0 = 0; r0 < N_; r0 += qr) {
        score_kernel<<<dim3(N_ / 128, qr / 128, B_), 256, 0, stream>>>(
            thetaH, phiH, cnt, list, SH, r0, qr);
        select_kernel<<<dim3(qr, B_), 256, 0, stream>>>(SH, cnt, r0, qr);
        pv_kernel<<<dim3(qr / 64, KS_PV, B_), 256, 0, stream>>>(
            SH, gWTH, cnt, gc_part, r0, qr);
        scatter_kernel<<<dim3(qr * IC_ / 256, B_), 256, 0, stream>>>(
            gc_part, cnt, list, gc, r0, qr);
    }

    y_kernel<<<dim3(N_ / 64, C_ / 64, B_), 256, 0, stream>>>(gc, Wout, bout, y);
    bn_stats_kernel<<<dim3(C_), 256, 0, stream>>>(y, mean, rsig);
    final_kernel<<<dim3(B_ * C_ * N_ / 256), 256, 0, stream>>>(
        x, y, mean, rsig, gamma, beta, out);
}

// Round 13
// 129.292 us; speedup vs baseline: 3.0576x; 1.0941x over previous
//
#include <hip/hip_runtime.h>

#define B_ 2
#define C_ 256
#define IC_ 128
#define N_ 4096
#define KSEL 2048
#define KS_PV 8

// fixed workspace offsets (floats); SH + gc_part sized at runtime
#define OFF_GC    0u          // gc f32 [B][N][IC]
#define OFF_Y     1048576u    // y  f32 [B][C][N]
#define OFF_MEAN  3145728u
#define OFF_RSIG  3145984u
#define OFF_CNT   3146240u
#define OFF_LIST  3146304u    // int[B*N]
#define OFF_RANK  3154496u    // int[B*N]
#define OFF_THB   3162688u    // theta f16 [B][N][IC]
#define OFF_PHB   3686976u    // phi   f16 [B][N][IC]
#define OFF_GWT   4211264u    // gW^T  f16 [B][IC][N]
#define OFF_XTH   4735552u    // x^T   f16 [B][N][C]
#define OFF_WALL  5784128u    // {Wth,Weff,Wph} f16 [384][256]
#define OFF_BALL  5833280u    // f32 [384]
#define OFF_S     5833664u    // SH f16 [B][qr][N]; then gc_part f16

typedef __attribute__((ext_vector_type(8))) _Float16 f16x8;
typedef __attribute__((ext_vector_type(4))) float f32x4;

__device__ __forceinline__ unsigned short f2h(float f) {
    union { _Float16 h; unsigned short u; } cv;
    cv.h = (_Float16)f;
    return cv.u;
}
__device__ __forceinline__ float h2f(unsigned short u) {
    union { unsigned short u; _Float16 h; } cv;
    cv.u = u;
    return (float)cv.h;
}

// ---------------------------------------------------------------------------
// prep: fused {xT transpose (blocks 0..511), W pack + Weff (512..895),
//              hard-row compaction + rank map (896..897)}
// ---------------------------------------------------------------------------
__global__ __launch_bounds__(256) void prep_kernel(
    const float* __restrict__ x, unsigned short* __restrict__ xTH,
    const float* __restrict__ Wth, const float* __restrict__ bth,
    const float* __restrict__ Wg,  const float* __restrict__ bg,
    const float* __restrict__ Wgcn,
    const float* __restrict__ Wph, const float* __restrict__ bph,
    unsigned short* __restrict__ WallH, float* __restrict__ ball,
    const float* __restrict__ hard_map, int* __restrict__ cnt,
    int* __restrict__ list, int* __restrict__ rank)
{
    __shared__ float Xs[64][65];
    __shared__ int wsum[4];
    const int bid = blockIdx.x;
    const int t = threadIdx.x;

    if (bid < 512) {
        // ---- xT: x [b][c][n] f32 -> xTH [b][n][c] f16, 64x64 tile ----
        const int n0 = (bid & 63) * 64;
        const int c0 = ((bid >> 6) & 3) * 64;
        const int b  = bid >> 8;
#pragma unroll
        for (int s = 0; s < 4; ++s) {
            int e4 = t + 256 * s;
            int cc = e4 >> 4, c4 = e4 & 15;
            float4 v = *(const float4*)&x[((size_t)b * C_ + c0 + cc) * N_ + n0 + c4 * 4];
            Xs[cc][c4 * 4 + 0] = v.x; Xs[cc][c4 * 4 + 1] = v.y;
            Xs[cc][c4 * 4 + 2] = v.z; Xs[cc][c4 * 4 + 3] = v.w;
        }
        __syncthreads();
#pragma unroll
        for (int s = 0; s < 4; ++s) {
            int e = t + 256 * s;
            int nn = e >> 4, c4 = e & 15;
            ushort4 h;
            h.x = f2h(Xs[c4 * 4 + 0][nn]);
            h.y = f2h(Xs[c4 * 4 + 1][nn]);
            h.z = f2h(Xs[c4 * 4 + 2][nn]);
            h.w = f2h(Xs[c4 * 4 + 3][nn]);
            *(ushort4*)&xTH[((size_t)b * N_ + n0 + nn) * C_ + c0 + c4 * 4] = h;
        }
    } else if (bid < 896) {
        // ---- W pack: {Wth, Wgcn^T.Wg, Wph} -> WallH [384][256] + ball ----
        const int o = bid - 512;
        const int c = t;
        const int oo = o & 127;
        float wv, bv;
        if (o < 128) {
            wv = Wth[oo * C_ + c];
            bv = bth[oo];
        } else if (o < 256) {
            float acc = 0.f;
            for (int i = 0; i < IC_; ++i)
                acc = fmaf(Wgcn[i * IC_ + oo], Wg[i * C_ + c], acc);
            wv = acc;
            float bacc = 0.f;
            for (int i = 0; i < IC_; ++i)
                bacc = fmaf(Wgcn[i * IC_ + oo], bg[i], bacc);
            bv = bacc;
        } else {
            wv = Wph[oo * C_ + c];
            bv = bph[oo];
        }
        WallH[o * C_ + c] = f2h(wv);
        if (c == 0) ball[o] = bv;
    } else {
        // ---- compaction: 256 threads x 16 elements, atomic-free scan ----
        const int b = bid - 896;
        const int lane = t & 63, wid = t >> 6;
        const float* hm = hard_map + (size_t)b * N_;
        int flags[16];
        int c = 0;
#pragma unroll
        for (int q = 0; q < 4; ++q) {
            float4 v = *(const float4*)&hm[t * 16 + q * 4];
            flags[q * 4 + 0] = v.x > 0.5f;
            flags[q * 4 + 1] = v.y > 0.5f;
            flags[q * 4 + 2] = v.z > 0.5f;
            flags[q * 4 + 3] = v.w > 0.5f;
            c += flags[q * 4] + flags[q * 4 + 1] + flags[q * 4 + 2] + flags[q * 4 + 3];
        }
        int xv = c;
#pragma unroll
        for (int off = 1; off < 64; off <<= 1) {
            int y = __shfl_up(xv, off);
            if (lane >= off) xv += y;
        }
        if (lane == 63) wsum[wid] = xv;
        __syncthreads();
        int base = 0;
        for (int ww = 0; ww < wid; ++ww) base += wsum[ww];
        int pos = base + xv - c;
        int* lst = list + b * N_;
        int* rnk = rank + b * N_;
#pragma unroll
        for (int e = 0; e < 16; ++e) {
            int n = t * 16 + e;
            if (flags[e]) { lst[pos] = n; rnk[n] = pos; ++pos; }
            else rnk[n] = -1;
        }
        if (t == 0) {
            int tot = 0;
#pragma unroll
            for (int ww = 0; ww < 4; ++ww) tot += wsum[ww];
            cnt[b] = tot;
        }
    }
}

// ---------------------------------------------------------------------------
// proj (MFMA f16): out[o][n] = WallH[pj-chunk] . xT, K=256.
// grid (N/128, 3, B)
// ---------------------------------------------------------------------------
__global__ __launch_bounds__(256) void proj_kernel(
    const unsigned short* __restrict__ xTH,
    const unsigned short* __restrict__ WallH, const float* __restrict__ ball,
    unsigned short* __restrict__ thetaH, unsigned short* __restrict__ gWTH,
    unsigned short* __restrict__ phiH)
{
    __shared__ unsigned short Xt[128][72];
    __shared__ unsigned short Wt[128][72];
    const int n0 = blockIdx.x * 128;
    const int pj = blockIdx.y;
    const int b  = blockIdx.z;
    const int t = threadIdx.x, w = t >> 6, lane = t & 63;
    const int lrow = lane & 15, lk = (lane >> 4) * 8;
    const int wA = (w >> 1) * 64, wB = (w & 1) * 64;

    f32x4 acc[4][4];
#pragma unroll
    for (int u = 0; u < 4; ++u)
#pragma unroll
        for (int v = 0; v < 4; ++v) acc[u][v] = (f32x4)(0.f);

    for (int kc = 0; kc < C_; kc += 64) {
        __syncthreads();
#pragma unroll
        for (int s = 0; s < 4; ++s) {
            int e4 = t + 256 * s;
            int r = e4 >> 3, k8 = e4 & 7;
            *(float4*)&Xt[r][k8 * 8] =
                *(const float4*)&xTH[((size_t)b * N_ + n0 + r) * C_ + kc + k8 * 8];
        }
#pragma unroll
        for (int s = 0; s < 4; ++s) {
            int e4 = t + 256 * s;
            int r = e4 >> 3, k8 = e4 & 7;
            *(float4*)&Wt[r][k8 * 8] =
                *(const float4*)&WallH[(size_t)(pj * 128 + r) * C_ + kc + k8 * 8];
        }
        __syncthreads();

#pragma unroll
        for (int kstep = 0; kstep < 2; ++kstep) {
            const int kk = kstep * 32 + lk;
            f16x8 af[4], bf[4];
            if (pj != 1) {
#pragma unroll
                for (int u = 0; u < 4; ++u)
                    af[u] = *(const f16x8*)&Wt[wA + u * 16 + lrow][kk];
#pragma unroll
                for (int v = 0; v < 4; ++v)
                    bf[v] = *(const f16x8*)&Xt[wB + v * 16 + lrow][kk];
            } else {
#pragma unroll
                for (int u = 0; u < 4; ++u)
                    af[u] = *(const f16x8*)&Xt[wA + u * 16 + lrow][kk];
#pragma unroll
                for (int v = 0; v < 4; ++v)
                    bf[v] = *(const f16x8*)&Wt[wB + v * 16 + lrow][kk];
            }
#pragma unroll
            for (int u = 0; u < 4; ++u)
#pragma unroll
                for (int v = 0; v < 4; ++v)
                    acc[u][v] = __builtin_amdgcn_mfma_f32_16x16x32_f16(
                        af[u], bf[v], acc[u][v], 0, 0, 0);
        }
    }

    const int crow = (lane >> 4) * 4;
    if (pj != 1) {
        unsigned short* dst = (pj == 0) ? thetaH : phiH;
        const int bb2 = (pj == 0) ? 0 : 256;
#pragma unroll
        for (int u = 0; u < 4; ++u) {
            const int ob = wA + u * 16 + crow;
            float b0 = ball[bb2 + ob + 0], b1 = ball[bb2 + ob + 1];
            float b2 = ball[bb2 + ob + 2], b3 = ball[bb2 + ob + 3];
#pragma unroll
            for (int v = 0; v < 4; ++v) {
                const int n = n0 + wB + v * 16 + lrow;
                ushort4 h;
                h.x = f2h(acc[u][v][0] + b0);
                h.y = f2h(acc[u][v][1] + b1);
                h.z = f2h(acc[u][v][2] + b2);
                h.w = f2h(acc[u][v][3] + b3);
                *(ushort4*)&dst[((size_t)b * N_ + n) * IC_ + ob] = h;
            }
        }
    } else {
#pragma unroll
        for (int v = 0; v < 4; ++v) {
            const int o = wB + v * 16 + lrow;
            const float bo = ball[128 + o];
#pragma unroll
            for (int u = 0; u < 4; ++u) {
                const int nb = n0 + wA + u * 16 + crow;
                ushort4 h;
                h.x = f2h(acc[u][v][0] + bo);
                h.y = f2h(acc[u][v][1] + bo);
                h.z = f2h(acc[u][v][2] + bo);
                h.w = f2h(acc[u][v][3] + bo);
                *(ushort4*)&gWTH[((size_t)b * IC_ + o) * N_ + nb] = h;
            }
        }
    }
}

// ---------------------------------------------------------------------------
// score (MFMA f16): SH[b][lr][m] = theta_row(lr) . phi[:,m], f16 out.
// grid (N/128, qr/128, B)
// ---------------------------------------------------------------------------
__global__ __launch_bounds__(256) void score_kernel(
    const unsigned short* __restrict__ thetaH,
    const unsigned short* __restrict__ phiH,
    const int* __restrict__ cnt, const int* __restrict__ list,
    unsigned short* __restrict__ SH, int r0base, int qr)
{
    __shared__ unsigned short Th[128][136];
    __shared__ unsigned short Ph[128][136];
    __shared__ int sIdx[128];

    const int b = blockIdx.z;
    const int count = cnt[b];
    const int lr0 = blockIdx.y * 128;
    if (r0base + lr0 >= count) return;
    const int m0 = blockIdx.x * 128;
    const int t = threadIdx.x;
    const int w = t >> 6, lane = t & 63;

    if (t < 128) {
        int gr = r0base + lr0 + t;
        sIdx[t] = (gr < count) ? list[b * N_ + gr] : -1;
    }
    __syncthreads();

#pragma unroll
    for (int s = 0; s < 8; ++s) {
        int e4 = t + 256 * s;
        int r = e4 >> 4, k4 = e4 & 15;
        int gr = sIdx[r];
        float4 v = make_float4(0.f, 0.f, 0.f, 0.f);
        if (gr >= 0)
            v = *(const float4*)&thetaH[((size_t)b * N_ + gr) * IC_ + k4 * 8];
        *(float4*)&Th[r][k4 * 8] = v;
    }
#pragma unroll
    for (int s = 0; s < 8; ++s) {
        int e4 = t + 256 * s;
        int r = e4 >> 4, k4 = e4 & 15;
        *(float4*)&Ph[r][k4 * 8] =
            *(const float4*)&phiH[((size_t)b * N_ + m0 + r) * IC_ + k4 * 8];
    }
    __syncthreads();

    const int wm = (w >> 1) * 64, wr = (w & 1) * 64;
    const int lrow = lane & 15, lk = (lane >> 4) * 8;

    f32x4 acc[4][4];
#pragma unroll
    for (int u = 0; u < 4; ++u)
#pragma unroll
        for (int v = 0; v < 4; ++v) acc[u][v] = (f32x4)(0.f);

#pragma unroll
    for (int ks = 0; ks < 4; ++ks) {
        const int kk = ks * 32 + lk;
        f16x8 af[4], bf[4];
#pragma unroll
        for (int u = 0; u < 4; ++u)
            af[u] = *(const f16x8*)&Ph[wm + u * 16 + lrow][kk];
#pragma unroll
        for (int v = 0; v < 4; ++v)
            bf[v] = *(const f16x8*)&Th[wr + v * 16 + lrow][kk];
#pragma unroll
        for (int u = 0; u < 4; ++u)
#pragma unroll
            for (int v = 0; v < 4; ++v)
                acc[u][v] = __builtin_amdgcn_mfma_f32_16x16x32_f16(
                    af[u], bf[v], acc[u][v], 0, 0, 0);
    }

    const int crow = (lane >> 4) * 4;
#pragma unroll
    for (int u = 0; u < 4; ++u) {
        const int mb = m0 + wm + u * 16 + crow;
#pragma unroll
        for (int v = 0; v < 4; ++v) {
            const int r = lr0 + wr + v * 16 + lrow;
            ushort4 h;
            h.x = f2h(acc[u][v][0]);
            h.y = f2h(acc[u][v][1]);
            h.z = f2h(acc[u][v][2]);
            h.w = f2h(acc[u][v][3]);
            *(ushort4*)&SH[((size_t)b * qr + r) * N_ + mb] = h;
        }
    }
}

// ---------------------------------------------------------------------------
// select: exact kth-largest radix select (2x8-bit passes on monotone u16)
// + softmax; writes P f16 in place. grid (qr, B)
// ---------------------------------------------------------------------------
__global__ __launch_bounds__(256) void select_kernel(
    unsigned short* __restrict__ SH, const int* __restrict__ cnt,
    int r0base, int qr)
{
    __shared__ unsigned int sHist[4][256];
    __shared__ unsigned int sWsum[4];
    __shared__ float sRed[8];
    __shared__ unsigned int sPrefix, sRemain;

    const int b = blockIdx.y;
    const int lr = blockIdx.x;
    if (r0base + lr >= cnt[b]) return;
    const int t = threadIdx.x, lane = t & 63, wid = t >> 6;

    uint4* row = (uint4*)(SH + ((size_t)b * qr + lr) * N_);
    uint4 rv[2];
    rv[0] = row[t];
    rv[1] = row[t + 256];

    float sv[16];
    unsigned int mu[16];
#pragma unroll
    for (int q = 0; q < 2; ++q) {
        const unsigned int* pu = (const unsigned int*)&rv[q];
#pragma unroll
        for (int dw = 0; dw < 4; ++dw) {
            unsigned int u = pu[dw];
            unsigned short h0 = (unsigned short)(u & 0xffffu);
            unsigned short h1 = (unsigned short)(u >> 16);
            int e = q * 8 + dw * 2;
            sv[e]     = h2f(h0);
            sv[e + 1] = h2f(h1);
            mu[e]     = (h0 & 0x8000u) ? (unsigned int)((~h0) & 0xffffu)
                                       : (unsigned int)(h0 | 0x8000u);
            mu[e + 1] = (h1 & 0x8000u) ? (unsigned int)((~h1) & 0xffffu)
                                       : (unsigned int)(h1 | 0x8000u);
        }
    }

    float m = -3.4e38f;
#pragma unroll
    for (int e = 0; e < 16; ++e) m = fmaxf(m, sv[e]);
#pragma unroll
    for (int off = 32; off > 0; off >>= 1) m = fmaxf(m, __shfl_xor(m, off));
    if (lane == 0) sRed[wid] = m;
    __syncthreads();
    m = fmaxf(fmaxf(sRed[0], sRed[1]), fmaxf(sRed[2], sRed[3]));

    unsigned int prefix = 0u;
    unsigned int remain = KSEL;
    for (int d = 1; d >= 0; --d) {
        __syncthreads();
#pragma unroll
        for (int ww = 0; ww < 4; ++ww) sHist[ww][t] = 0u;
        __syncthreads();
#pragma unroll
        for (int e = 0; e < 16; ++e) {
            if ((mu[e] >> (8 * (d + 1))) == prefix)
                atomicAdd(&sHist[wid][(mu[e] >> (8 * d)) & 255u], 1u);
        }
        __syncthreads();
        unsigned int x = sHist[0][t] + sHist[1][t] + sHist[2][t] + sHist[3][t];
        unsigned int own = x;
#pragma unroll
        for (int off = 1; off < 64; off <<= 1) {
            unsigned int y = __shfl_down(x, off);
            if (lane + off < 64) x += y;
        }
        if (lane == 0) sWsum[wid] = x;
        __syncthreads();
        for (int ww = wid + 1; ww < 4; ++ww) x += sWsum[ww];
        unsigned int nxt = x - own;
        if (x >= remain && nxt < remain) {
            sPrefix = (prefix << 8) | (unsigned int)t;
            sRemain = remain - nxt;
        }
        __syncthreads();
        prefix = sPrefix;
        remain = sRemain;
    }
    const unsigned int tu = prefix;

    float z = 0.f, ssel = 0.f;
#pragma unroll
    for (int e = 0; e < 16; ++e) {
        float ex = expf(sv[e] - m);
        z += ex;
        if (mu[e] >= tu) ssel += ex;
    }
#pragma unroll
    for (int off = 32; off > 0; off >>= 1) {
        z    += __shfl_xor(z, off);
        ssel += __shfl_xor(ssel, off);
    }
    __syncthreads();
    if (lane == 0) { sRed[wid] = z; sRed[4 + wid] = ssel; }
    __syncthreads();
    const float zt = sRed[0] + sRed[1] + sRed[2] + sRed[3];
    const float st = sRed[4] + sRed[5] + sRed[6] + sRed[7];
    const float inv = 1.f / (st + 1e-6f * zt);

#pragma unroll
    for (int q = 0; q < 2; ++q) {
        unsigned int* pu = (unsigned int*)&rv[q];
#pragma unroll
        for (int dw = 0; dw < 4; ++dw) {
            int e = q * 8 + dw * 2;
            unsigned int p0 = (mu[e] >= tu) ? (unsigned int)f2h(expf(sv[e] - m) * inv) : 0u;
            unsigned int p1 = (mu[e + 1] >= tu) ? (unsigned int)f2h(expf(sv[e + 1] - m) * inv) : 0u;
            pu[dw] = p0 | (p1 << 16);
        }
    }
    row[t]       = rv[0];
    row[t + 256] = rv[1];
}

// ---------------------------------------------------------------------------
// pv (MFMA f16, split-K=8): gc_partH[b][ks][lr][i] (f16) over ks*512..+512.
// grid (qr/64, 8, B)
// ---------------------------------------------------------------------------
__global__ __launch_bounds__(256) void pv_kernel(
    const unsigned short* __restrict__ SH, const unsigned short* __restrict__ gWTH,
    const int* __restrict__ cnt, unsigned short* __restrict__ gc_partH,
    int r0base, int qr)
{
    __shared__ unsigned short Pt[64][72];
    __shared__ unsigned short Gt[128][72];

    const int b = blockIdx.z;
    const int count = cnt[b];
    const int lr0 = blockIdx.x * 64;
    if (r0base + lr0 >= count) return;
    const int ks = blockIdx.y;
    const int t = threadIdx.x;
    const int w = t >> 6, lane = t & 63;
    const int lrow = lane & 15, lk = (lane >> 4) * 8;
    const int wiA = (w & 1) * 64, wrB = (w >> 1) * 32;

    f32x4 acc[4][2];
#pragma unroll
    for (int u = 0; u < 4; ++u)
#pragma unroll
        for (int v = 0; v < 2; ++v) acc[u][v] = (f32x4)(0.f);

    for (int jc = ks * 512; jc < ks * 512 + 512; jc += 64) {
        __syncthreads();
#pragma unroll
        for (int s = 0; s < 2; ++s) {
            int e4 = t + 256 * s;
            int r = e4 >> 3, k8 = e4 & 7;
            *(float4*)&Pt[r][k8 * 8] =
                *(const float4*)&SH[((size_t)b * qr + lr0 + r) * N_ + jc + k8 * 8];
        }
#pragma unroll
        for (int s = 0; s < 4; ++s) {
            int e4 = t + 256 * s;
            int i = e4 >> 3, k8 = e4 & 7;
            *(float4*)&Gt[i][k8 * 8] =
                *(const float4*)&gWTH[((size_t)b * IC_ + i) * N_ + jc + k8 * 8];
        }
        __syncthreads();

#pragma unroll
        for (int kstep = 0; kstep < 2; ++kstep) {
            const int kk = kstep * 32 + lk;
            f16x8 af[4], bf[2];
#pragma unroll
            for (int u = 0; u < 4; ++u)
                af[u] = *(const f16x8*)&Gt[wiA + u * 16 + lrow][kk];
#pragma unroll
            for (int v = 0; v < 2; ++v)
                bf[v] = *(const f16x8*)&Pt[wrB + v * 16 + lrow][kk];
#pragma unroll
            for (int u = 0; u < 4; ++u)
#pragma unroll
                for (int v = 0; v < 2; ++v)
                    acc[u][v] = __builtin_amdgcn_mfma_f32_16x16x32_f16(
                        af[u], bf[v], acc[u][v], 0, 0, 0);
        }
    }

    const int crow = (lane >> 4) * 4;
#pragma unroll
    for (int u = 0; u < 4; ++u) {
        const int ib = wiA + u * 16 + crow;
#pragma unroll
        for (int v = 0; v < 2; ++v) {
            const int r = lr0 + wrB + v * 16 + lrow;
            ushort4 h;
            h.x = f2h(acc[u][v][0]);
            h.y = f2h(acc[u][v][1]);
            h.z = f2h(acc[u][v][2]);
            h.w = f2h(acc[u][v][3]);
            *(ushort4*)&gc_partH[(((size_t)b * KS_PV + ks) * qr + r) * IC_ + ib] = h;
        }
    }
}

// ---------------------------------------------------------------------------
// dense scatter: for every (b,n,i) — rank<0 -> 0 (pass 0 only), else reduce
// f16 split-K partials + ReLU. grid (N*IC/256, B)
// ---------------------------------------------------------------------------
__global__ __launch_bounds__(256) void scatter_kernel(
    const unsigned short* __restrict__ gc_partH, const int* __restrict__ rank,
    float* __restrict__ gc, int r0base, int qr)
{
    const int b = blockIdx.y;
    int idx = blockIdx.x * 256 + threadIdx.x;
    int n = idx >> 7, i = idx & 127;
    int r = rank[b * N_ + n];
    if (r < 0) {
        if (r0base == 0) gc[((size_t)b * N_ + n) * IC_ + i] = 0.f;
        return;
    }
    if (r < r0base || r >= r0base + qr) return;
    const int lr = r - r0base;
    float v = 0.f;
#pragma unroll
    for (int ks = 0; ks < KS_PV; ++ks)
        v += h2f(gc_partH[(((size_t)b * KS_PV + ks) * qr + lr) * IC_ + i]);
    gc[((size_t)b * N_ + n) * IC_ + i] = fmaxf(v, 0.f);
}

// ---------------------------------------------------------------------------
// y[b,c,n] = Wout[c,:] . gc[b,n,:] + bout[c].  64c x 64n tiles.
// ---------------------------------------------------------------------------
__global__ __launch_bounds__(256) void y_kernel(
    const float* __restrict__ gc, const float* __restrict__ Wout,
    const float* __restrict__ bout, float* __restrict__ y)
{
    __shared__ float Wt[64][33];
    __shared__ float Gt[32][68];
    const int n0 = blockIdx.x * 64;
    const int c0 = blockIdx.y * 64;
    const int b  = blockIdx.z;
    const int t = threadIdx.x;
    const int tx = t & 15, ty = t >> 4;

    float acc[4][4];
#pragma unroll
    for (int u = 0; u < 4; ++u)
#pragma unroll
        for (int v = 0; v < 4; ++v) acc[u][v] = 0.f;

    for (int kc = 0; kc < IC_; kc += 32) {
        __syncthreads();
#pragma unroll
        for (int s = 0; s < 2; ++s) {
            int e4 = t + 256 * s;
            int c = e4 >> 3, k4 = e4 & 7;
            float4 ww = *(const float4*)&Wout[(size_t)(c0 + c) * IC_ + kc + k4 * 4];
            Wt[c][k4 * 4 + 0] = ww.x; Wt[c][k4 * 4 + 1] = ww.y;
            Wt[c][k4 * 4 + 2] = ww.z; Wt[c][k4 * 4 + 3] = ww.w;
        }
#pragma unroll
        for (int s = 0; s < 2; ++s) {
            int e4 = t + 256 * s;
            int nn = e4 >> 3, k4 = e4 & 7;
            float4 g = *(const float4*)&gc[((size_t)b * N_ + n0 + nn) * IC_ + kc + k4 * 4];
            Gt[k4 * 4 + 0][nn] = g.x; Gt[k4 * 4 + 1][nn] = g.y;
            Gt[k4 * 4 + 2][nn] = g.z; Gt[k4 * 4 + 3][nn] = g.w;
        }
        __syncthreads();

#pragma unroll 4
        for (int k = 0; k < 32; ++k) {
            float a[4];
#pragma unroll
            for (int u = 0; u < 4; ++u) a[u] = Wt[ty * 4 + u][k];
            const float4 g4 = *(const float4*)&Gt[k][tx * 4];
            const float gm[4] = {g4.x, g4.y, g4.z, g4.w};
#pragma unroll
            for (int u = 0; u < 4; ++u)
#pragma unroll
                for (int v = 0; v < 4; ++v)
                    acc[u][v] = fmaf(a[u], gm[v], acc[u][v]);
        }
    }

#pragma unroll
    for (int u = 0; u < 4; ++u) {
        const int c = c0 + ty * 4 + u;
        const float bo = bout[c];
        *(float4*)&y[((size_t)b * C_ + c) * N_ + n0 + tx * 4] =
            make_float4(acc[u][0] + bo, acc[u][1] + bo,
                        acc[u][2] + bo, acc[u][3] + bo);
    }
}

// ---------------------------------------------------------------------------
// BatchNorm stats per channel
// ---------------------------------------------------------------------------
__global__ __launch_bounds__(256) void bn_stats_kernel(
    const float* __restrict__ y, float* __restrict__ mean,
    float* __restrict__ rsig)
{
    __shared__ float sr[8];
    const int c = blockIdx.x, t = threadIdx.x;
    const int lane = t & 63, wid = t >> 6;
    float s = 0.f, ss = 0.f;
    for (int b = 0; b < B_; ++b) {
        const float* yr = y + ((size_t)b * C_ + c) * N_;
        for (int n = t; n < N_; n += 256) {
            float v = yr[n];
            s += v; ss = fmaf(v, v, ss);
        }
    }
#pragma unroll
    for (int off = 32; off > 0; off >>= 1) {
        s  += __shfl_xor(s, off);
        ss += __shfl_xor(ss, off);
    }
    if (lane == 0) { sr[wid] = s; sr[4 + wid] = ss; }
    __syncthreads();
    if (t == 0) {
        float st  = sr[0] + sr[1] + sr[2] + sr[3];
        float sst = sr[4] + sr[5] + sr[6] + sr[7];
        float mu  = st / (float)(B_ * N_);
        float var = sst / (float)(B_ * N_) - mu * mu;
        mean[c] = mu;
        rsig[c] = rsqrtf(var + 1e-5f);
    }
}

// ---------------------------------------------------------------------------
// out = x + gamma*(y-mean)*rsig + beta
// ---------------------------------------------------------------------------
__global__ __launch_bounds__(256) void final_kernel(
    const float* __restrict__ x, const float* __restrict__ y,
    const float* __restrict__ mean, const float* __restrict__ rsig,
    const float* __restrict__ gamma, const float* __restrict__ beta,
    float* __restrict__ out)
{
    int idx = blockIdx.x * 256 + threadIdx.x;
    if (idx >= B_ * C_ * N_) return;
    int c = (idx >> 12) & (C_ - 1);
    out[idx] = x[idx] + fmaf(gamma[c], (y[idx] - mean[c]) * rsig[c], beta[c]);
}

extern "C" void kernel_launch(void* const* d_in, const int* in_sizes, int n_in,
                              void* d_out, int out_size, void* d_ws, size_t ws_size,
                              hipStream_t stream)
{
    const float* x     = (const float*)d_in[0];
    const float* hard  = (const float*)d_in[1];
    const float* Wg    = (const float*)d_in[2];
    const float* bg    = (const float*)d_in[3];
    const float* Wth   = (const float*)d_in[4];
    const float* bth   = (const float*)d_in[5];
    const float* Wph   = (const float*)d_in[6];
    const float* bph   = (const float*)d_in[7];
    const float* Wgcn  = (const float*)d_in[8];
    const float* Wout  = (const float*)d_in[9];
    const float* bout  = (const float*)d_in[10];
    const float* gamma = (const float*)d_in[11];
    const float* beta  = (const float*)d_in[12];
    float* out = (float*)d_out;
    float* ws  = (float*)d_ws;

    float* gc    = ws + OFF_GC;
    float* y     = ws + OFF_Y;
    float* mean  = ws + OFF_MEAN;
    float* rsig  = ws + OFF_RSIG;
    int*   cnt   = (int*)(ws + OFF_CNT);
    int*   list  = (int*)(ws + OFF_LIST);
    int*   rank  = (int*)(ws + OFF_RANK);
    unsigned short* thetaH = (unsigned short*)(ws + OFF_THB);
    unsigned short* phiH   = (unsigned short*)(ws + OFF_PHB);
    unsigned short* gWTH   = (unsigned short*)(ws + OFF_GWT);
    unsigned short* xTH    = (unsigned short*)(ws + OFF_XTH);
    unsigned short* WallH  = (unsigned short*)(ws + OFF_WALL);
    float* ball  = ws + OFF_BALL;
    unsigned short* SH = (unsigned short*)(ws + OFF_S);

    // runtime-adaptive row-block: SH = qr*2048 floats/batch-pair, partials f16
    const size_t wsf = ws_size / sizeof(float);
    int qr;
    unsigned short* gc_partH;
    if (wsf >= OFF_S + (size_t)4096 * 6144) {            // >= 124 MB total
        qr = 4096; gc_partH = (unsigned short*)(ws + OFF_S + (size_t)4096 * 4096);
    } else if (wsf >= OFF_S + (size_t)2048 * 6144) {
        qr = 2048; gc_partH = (unsigned short*)(ws + OFF_S + (size_t)2048 * 4096);
    } else {
        qr = 1024; gc_partH = (unsigned short*)out;  // 4.2 MB < 8 MB d_out;
                                                     // overwritten by final
    }

    prep_kernel<<<dim3(898), 256, 0, stream>>>(
        x, xTH, Wth, bth, Wg, bg, Wgcn, Wph, bph, WallH, ball,
        hard, cnt, list, rank);
    proj_kernel<<<dim3(N_ / 128, 3, B_), 256, 0, stream>>>(
        xTH, WallH, ball, thetaH, gWTH, phiH);

    for (int r0 = 0; r0 < N_; r0 += qr) {
        score_kernel<<<dim3(N_ / 128, qr / 128, B_), 256, 0, stream>>>(
            thetaH, phiH, cnt, list, SH, r0, qr);
        select_kernel<<<dim3(qr, B_), 256, 0, stream>>>(SH, cnt, r0, qr);
        pv_kernel<<<dim3(qr / 64, KS_PV, B_), 256, 0, stream>>>(
            SH, gWTH, cnt, gc_partH, r0, qr);
        scatter_kernel<<<dim3(N_ * IC_ / 256, B_), 256, 0, stream>>>(
            gc_partH, rank, gc, r0, qr);
    }

    y_kernel<<<dim3(N_ / 64, C_ / 64, B_), 256, 0, stream>>>(gc, Wout, bout, y);
    bn_stats_kernel<<<dim3(C_), 256, 0, stream>>>(y, mean, rsig);
    final_kernel<<<dim3(B_ * C_ * N_ / 256), 256, 0, stream>>>(
        x, y, mean, rsig, gamma, beta, out);
}